// Round 18
// baseline (672.644 us; speedup 1.0000x reference)
//
#include <hip/hip_runtime.h>
#include <hip/hip_bf16.h>
#include <math.h>

#define B_   16
#define L_   1024
#define SCALE_ 0.17677669529663687f   // 1/sqrt(32)

// ---------------------------------------------------------------------------
// MT19937 -> PROB_IDX (35840 draws of genrand_int32() & 1023, seed 0)
// ---------------------------------------------------------------------------
__global__ void mt_kernel(int* __restrict__ pidx) {
  __shared__ unsigned int mt[624];
  int tid = threadIdx.x;   // 256
  if (tid == 0) {
    unsigned int s = 0u;
    for (int i = 0; i < 624; ++i) {
      mt[i] = s;
      s = 1812433253u * (s ^ (s >> 30)) + (unsigned)(i + 1);
    }
  }
  __syncthreads();
  const unsigned int HI = 0x80000000u, LO = 0x7fffffffu, MM = 0x9908b0dfu;
  for (int blk = 0; blk < 58; ++blk) {
    unsigned int n0 = 0, n1 = 0, n2 = 0, old623 = 0;
    bool a0 = tid < 227, a2 = tid < 169;
    if (a0) {
      unsigned int y0 = (mt[tid] & HI) | (mt[tid + 1] & LO);
      n0 = mt[tid + 397] ^ (y0 >> 1) ^ ((y0 & 1u) ? MM : 0u);
      unsigned int y1 = (mt[tid + 227] & HI) | (mt[tid + 228] & LO);
      n1 = n0 ^ (y1 >> 1) ^ ((y1 & 1u) ? MM : 0u);
      if (a2) {
        unsigned int y2 = (mt[tid + 454] & HI) | (mt[tid + 455] & LO);
        n2 = n1 ^ (y2 >> 1) ^ ((y2 & 1u) ? MM : 0u);
      }
      if (tid == 169) old623 = mt[623];
    }
    __syncthreads();
    if (a0) {
      mt[tid] = n0;
      mt[tid + 227] = n1;
      if (a2) mt[tid + 454] = n2;
    }
    __syncthreads();
    if (tid == 169) {
      unsigned int y = (old623 & HI) | (mt[0] & LO);
      mt[623] = n1 ^ (y >> 1) ^ ((y & 1u) ? MM : 0u);
    }
    __syncthreads();
    for (int i = tid; i < 624; i += 256) {
      int g = blk * 624 + i;
      if (g < 35840) {
        unsigned int y = mt[i];
        y ^= y >> 11;
        y ^= (y << 7) & 0x9d2c5680u;
        y ^= (y << 15) & 0xefc60000u;
        y ^= y >> 18;
        pidx[g] = (int)(y & 1023u);
      }
    }
  }
}

// ---------------------------------------------------------------------------
// fp32 conv body (fallback path + conv1 slices). 2 ch x 8 t per thread.
// OUTPUT CHANNEL-MAJOR: out[b, c*1024 + t]. Blocks cover 64 t.
// ---------------------------------------------------------------------------
__device__ __forceinline__ void conv_body(const float* __restrict__ x,
                                          const float* __restrict__ w,
                                          const float* __restrict__ bias,
                                          float* __restrict__ out,
                                          float* smem, int b, int t0, int tid, int is1) {
  int cp = tid & 31;          // channels cp and cp+32
  int tg = tid >> 5;          // 0..7
  int tt0 = tg * 8;           // 8 t per thread
  float acc0[8], acc1[8];
  float b0v = bias[cp], b1v = bias[cp + 32];
  #pragma unroll
  for (int j = 0; j < 8; ++j) { acc0[j] = b0v; acc1[j] = b1v; }
  if (!is1) {
    float* xs = smem;            // [66][128]
    float* ws = smem + 8448;     // [64][52]
    for (int i = tid; i < 66 * 128; i += 256) {
      int r = i >> 7, d = i & 127;
      int t = t0 - 2 + r;
      xs[r * 128 + d] = (t >= 0) ? x[(size_t)b * 131072 + (size_t)t * 128 + d] : 0.0f;
    }
    for (int dc = 0; dc < 128; dc += 16) {
      __syncthreads();
      {
        int row = tid >> 2, sub = tid & 3;
        const float* wsrc = w + row * 384 + dc * 3 + sub * 12;
        float* wdst = ws + row * 52 + sub * 12;
        #pragma unroll
        for (int k = 0; k < 12; ++k) wdst[k] = wsrc[k];
      }
      __syncthreads();
      #pragma unroll
      for (int dl = 0; dl < 16; dl += 4) {
        int d0 = dc + dl;
        float4 xr[10];
        #pragma unroll
        for (int r = 0; r < 10; ++r) xr[r] = *(const float4*)&xs[(tt0 + r) * 128 + d0];
        float4 wa0 = *(const float4*)&ws[cp * 52 + dl * 3];
        float4 wa1 = *(const float4*)&ws[cp * 52 + dl * 3 + 4];
        float4 wa2 = *(const float4*)&ws[cp * 52 + dl * 3 + 8];
        float4 wb0 = *(const float4*)&ws[(cp + 32) * 52 + dl * 3];
        float4 wb1 = *(const float4*)&ws[(cp + 32) * 52 + dl * 3 + 4];
        float4 wb2 = *(const float4*)&ws[(cp + 32) * 52 + dl * 3 + 8];
        float w0r[12] = {wa0.x, wa0.y, wa0.z, wa0.w, wa1.x, wa1.y, wa1.z, wa1.w,
                         wa2.x, wa2.y, wa2.z, wa2.w};
        float w1r[12] = {wb0.x, wb0.y, wb0.z, wb0.w, wb1.x, wb1.y, wb1.z, wb1.w,
                         wb2.x, wb2.y, wb2.z, wb2.w};
        #pragma unroll
        for (int j = 0; j < 8; ++j) {
          float a0 = acc0[j], a1 = acc1[j];
          #pragma unroll
          for (int k = 0; k < 3; ++k) {
            float4 xv = xr[j + k];
            a0 = fmaf(w0r[0 + k], xv.x, a0);
            a0 = fmaf(w0r[3 + k], xv.y, a0);
            a0 = fmaf(w0r[6 + k], xv.z, a0);
            a0 = fmaf(w0r[9 + k], xv.w, a0);
            a1 = fmaf(w1r[0 + k], xv.x, a1);
            a1 = fmaf(w1r[3 + k], xv.y, a1);
            a1 = fmaf(w1r[6 + k], xv.z, a1);
            a1 = fmaf(w1r[9 + k], xv.w, a1);
          }
          acc0[j] = a0; acc1[j] = a1;
        }
      }
    }
  } else {
    float* xs = smem;            // [64][128]
    float* ws = smem + 8192;     // [64][36]
    for (int i = tid; i < 64 * 128; i += 256) {
      int r = i >> 7, d = i & 127;
      xs[r * 128 + d] = x[(size_t)b * 131072 + (size_t)(t0 + r) * 128 + d];
    }
    for (int dc = 0; dc < 128; dc += 32) {
      __syncthreads();
      {
        int row = tid >> 2, sub = tid & 3;
        const float* wsrc = w + row * 128 + dc + sub * 8;
        float* wdst = ws + row * 36 + sub * 8;
        #pragma unroll
        for (int k = 0; k < 8; ++k) wdst[k] = wsrc[k];
      }
      __syncthreads();
      #pragma unroll
      for (int dl = 0; dl < 32; dl += 4) {
        int d0 = dc + dl;
        float4 wv0 = *(const float4*)&ws[cp * 36 + dl];
        float4 wv1 = *(const float4*)&ws[(cp + 32) * 36 + dl];
        #pragma unroll
        for (int j = 0; j < 8; ++j) {
          float4 xv = *(const float4*)&xs[(tt0 + j) * 128 + d0];
          float a0 = acc0[j], a1 = acc1[j];
          a0 = fmaf(wv0.x, xv.x, a0);
          a0 = fmaf(wv0.y, xv.y, a0);
          a0 = fmaf(wv0.z, xv.z, a0);
          a0 = fmaf(wv0.w, xv.w, a0);
          a1 = fmaf(wv1.x, xv.x, a1);
          a1 = fmaf(wv1.y, xv.y, a1);
          a1 = fmaf(wv1.z, xv.z, a1);
          a1 = fmaf(wv1.w, xv.w, a1);
          acc0[j] = a0; acc1[j] = a1;
        }
      }
    }
  }
  float* op0 = out + (size_t)b * 65536 + (size_t)cp * 1024 + t0 + tt0;
  float* op1 = out + (size_t)b * 65536 + (size_t)(cp + 32) * 1024 + t0 + tt0;
  *(float4*)op0 = make_float4(acc0[0], acc0[1], acc0[2], acc0[3]);
  *(float4*)(op0 + 4) = make_float4(acc0[4], acc0[5], acc0[6], acc0[7]);
  *(float4*)op1 = make_float4(acc1[0], acc1[1], acc1[2], acc1[3]);
  *(float4*)(op1 + 4) = make_float4(acc1[4], acc1[5], acc1[6], acc1[7]);
}

// per-branch merged QKV conv (fallback path). z=0:Qconv3 z=1:Kconv3 z=2:Vconv1
__global__ __launch_bounds__(256, 3)
void qkv_conv_kernel(const float* __restrict__ xq, const float* __restrict__ xk,
                     const float* __restrict__ xv,
                     const float* __restrict__ wq, const float* __restrict__ bq,
                     const float* __restrict__ wk, const float* __restrict__ bk,
                     const float* __restrict__ wv, const float* __restrict__ bv,
                     float* __restrict__ qo, float* __restrict__ ko,
                     float* __restrict__ vo) {
  __shared__ float smem[11776];
  int which = blockIdx.z;
  const float* x = (which == 0) ? xq : (which == 1) ? xk : xv;
  const float* w = (which == 0) ? wq : (which == 1) ? wk : wv;
  const float* bias = (which == 0) ? bq : (which == 1) ? bk : bv;
  float* out = (which == 0) ? qo : (which == 1) ? ko : vo;
  conv_body(x, w, bias, out, smem, blockIdx.y, blockIdx.x * 64, threadIdx.x, which == 2);
}

struct ConvArgs {
  const float* x[3];
  const float* w[15];
  const float* bia[15];
  float* outbase;   // [slice][16*65536]
};

// conv1 slices (mega path): z in {2,5,8,11,14}
__global__ __launch_bounds__(256, 3)
void conv1_mega(ConvArgs a) {
  __shared__ float smem[11776];
  const int zmap[5] = {2, 5, 8, 11, 14};
  int z = zmap[blockIdx.z];
  float* out = a.outbase + (size_t)z * 1048576;
  conv_body(a.x[2], a.w[z], a.bia[z], out, smem, blockIdx.y, blockIdx.x * 64,
            threadIdx.x, 1);
}

// ---------------------------------------------------------------------------
// conv3 slices (mega path): 4 ch x 8 t per thread, blocks cover 128 t.
// x staged per-16-d chunk (xs[130][16]) with dl-slot XOR row-group swizzle:
// slot' = slot ^ ((row>>3)&3)  -> the 4 tg-groups of a wave hit disjoint
// bank quads (was a 4-way conflict: 8-row delta = 512B = 0 mod bank cycle).
// Per-channel accumulation order identical to conv_body -> bit-identical out.
// LDS: 130*16*4 + 64*52*4 = 8320 + 13312 = 21632 B
// ---------------------------------------------------------------------------
__global__ __launch_bounds__(256, 3)
void conv3_mega(ConvArgs a) {
  __shared__ float xs[130 * 16];
  __shared__ float ws[64 * 52];
  const int zmap[10] = {0, 1, 3, 4, 6, 7, 9, 10, 12, 13};
  int z = zmap[blockIdx.z];
  int which = z % 3;            // 0 or 1
  const float* x = a.x[which];
  const float* w = a.w[z];
  const float* bias = a.bia[z];
  float* out = a.outbase + (size_t)z * 1048576;
  int b = blockIdx.y, t0 = blockIdx.x * 128;
  int tid = threadIdx.x;
  int cg = tid & 15;            // channels cg, cg+16, cg+32, cg+48
  int tg = tid >> 4;            // 0..15
  int tt0 = tg * 8;
  int c0 = cg, c1 = cg + 16, c2 = cg + 32, c3 = cg + 48;
  float acc0[8], acc1[8], acc2[8], acc3[8];
  {
    float b0 = bias[c0], b1 = bias[c1], b2 = bias[c2], b3 = bias[c3];
    #pragma unroll
    for (int j = 0; j < 8; ++j) { acc0[j] = b0; acc1[j] = b1; acc2[j] = b2; acc3[j] = b3; }
  }
  for (int dc = 0; dc < 128; dc += 16) {
    __syncthreads();
    // stage weights: 64 ch x 48 floats for this d-chunk
    {
      int row = tid >> 2, sub = tid & 3;
      const float* wsrc = w + row * 384 + dc * 3 + sub * 12;
      float* wdst = ws + row * 52 + sub * 12;
      #pragma unroll
      for (int k = 0; k < 12; ++k) wdst[k] = wsrc[k];
    }
    // stage x chunk: rows t0-2 .. t0+127, d in [dc, dc+16), slot-swizzled
    for (int i = tid; i < 520; i += 256) {
      int row = i >> 2, db = i & 3;
      int t = t0 - 2 + row;
      float4 v = make_float4(0.f, 0.f, 0.f, 0.f);
      if (t >= 0) v = *(const float4*)(x + (size_t)b * 131072 + (size_t)t * 128 + dc + db * 4);
      int slot = db ^ ((row >> 3) & 3);
      *(float4*)&xs[row * 16 + slot * 4] = v;
    }
    __syncthreads();
    #pragma unroll
    for (int dl = 0; dl < 16; dl += 4) {
      float4 xr[10];
      #pragma unroll
      for (int r = 0; r < 10; ++r) {
        int row = tt0 + r;
        int slot = (dl >> 2) ^ ((row >> 3) & 3);
        xr[r] = *(const float4*)&xs[row * 16 + slot * 4];
      }
      float4 p0 = *(const float4*)&ws[c0 * 52 + dl * 3];
      float4 p1 = *(const float4*)&ws[c0 * 52 + dl * 3 + 4];
      float4 p2 = *(const float4*)&ws[c0 * 52 + dl * 3 + 8];
      float w0r[12] = {p0.x, p0.y, p0.z, p0.w, p1.x, p1.y, p1.z, p1.w, p2.x, p2.y, p2.z, p2.w};
      p0 = *(const float4*)&ws[c1 * 52 + dl * 3];
      p1 = *(const float4*)&ws[c1 * 52 + dl * 3 + 4];
      p2 = *(const float4*)&ws[c1 * 52 + dl * 3 + 8];
      float w1r[12] = {p0.x, p0.y, p0.z, p0.w, p1.x, p1.y, p1.z, p1.w, p2.x, p2.y, p2.z, p2.w};
      p0 = *(const float4*)&ws[c2 * 52 + dl * 3];
      p1 = *(const float4*)&ws[c2 * 52 + dl * 3 + 4];
      p2 = *(const float4*)&ws[c2 * 52 + dl * 3 + 8];
      float w2r[12] = {p0.x, p0.y, p0.z, p0.w, p1.x, p1.y, p1.z, p1.w, p2.x, p2.y, p2.z, p2.w};
      p0 = *(const float4*)&ws[c3 * 52 + dl * 3];
      p1 = *(const float4*)&ws[c3 * 52 + dl * 3 + 4];
      p2 = *(const float4*)&ws[c3 * 52 + dl * 3 + 8];
      float w3r[12] = {p0.x, p0.y, p0.z, p0.w, p1.x, p1.y, p1.z, p1.w, p2.x, p2.y, p2.z, p2.w};
      #pragma unroll
      for (int j = 0; j < 8; ++j) {
        float a0 = acc0[j], a1 = acc1[j], a2 = acc2[j], a3 = acc3[j];
        #pragma unroll
        for (int k = 0; k < 3; ++k) {
          float4 xv = xr[j + k];
          a0 = fmaf(w0r[0 + k], xv.x, a0);
          a0 = fmaf(w0r[3 + k], xv.y, a0);
          a0 = fmaf(w0r[6 + k], xv.z, a0);
          a0 = fmaf(w0r[9 + k], xv.w, a0);
          a1 = fmaf(w1r[0 + k], xv.x, a1);
          a1 = fmaf(w1r[3 + k], xv.y, a1);
          a1 = fmaf(w1r[6 + k], xv.z, a1);
          a1 = fmaf(w1r[9 + k], xv.w, a1);
          a2 = fmaf(w2r[0 + k], xv.x, a2);
          a2 = fmaf(w2r[3 + k], xv.y, a2);
          a2 = fmaf(w2r[6 + k], xv.z, a2);
          a2 = fmaf(w2r[9 + k], xv.w, a2);
          a3 = fmaf(w3r[0 + k], xv.x, a3);
          a3 = fmaf(w3r[3 + k], xv.y, a3);
          a3 = fmaf(w3r[6 + k], xv.z, a3);
          a3 = fmaf(w3r[9 + k], xv.w, a3);
        }
        acc0[j] = a0; acc1[j] = a1; acc2[j] = a2; acc3[j] = a3;
      }
    }
  }
  size_t obase = (size_t)b * 65536 + t0 + tt0;
  float* op;
  op = out + obase + (size_t)c0 * 1024;
  *(float4*)op = make_float4(acc0[0], acc0[1], acc0[2], acc0[3]);
  *(float4*)(op + 4) = make_float4(acc0[4], acc0[5], acc0[6], acc0[7]);
  op = out + obase + (size_t)c1 * 1024;
  *(float4*)op = make_float4(acc1[0], acc1[1], acc1[2], acc1[3]);
  *(float4*)(op + 4) = make_float4(acc1[4], acc1[5], acc1[6], acc1[7]);
  op = out + obase + (size_t)c2 * 1024;
  *(float4*)op = make_float4(acc2[0], acc2[1], acc2[2], acc2[3]);
  *(float4*)(op + 4) = make_float4(acc2[4], acc2[5], acc2[6], acc2[7]);
  op = out + obase + (size_t)c3 * 1024;
  *(float4*)op = make_float4(acc3[0], acc3[1], acc3[2], acc3[3]);
  *(float4*)(op + 4) = make_float4(acc3[4], acc3[5], acc3[6], acc3[7]);
}

// ---------------------------------------------------------------------------
// full attention, split-K partials, no-max softmax (scores bounded ~1)
// 128 threads, 2 q per thread (l0 = blk*256+tid, l1 = l0+128), 2 s per iter.
// ---------------------------------------------------------------------------
__global__ __launch_bounds__(128, 2)
void attn_full_part(const float* __restrict__ Q, const float* __restrict__ K,
                    const float* __restrict__ V, float* __restrict__ part,
                    int stile, int nstage) {
  __shared__ float Ks[128][32];
  __shared__ float Vs[128][32];
  int bh = blockIdx.z, b = bh >> 1, h = bh & 1;
  int tid = threadIdx.x;                // 128
  int l0 = blockIdx.x * 256 + tid;
  int s0 = blockIdx.y * stile;
  const float* Kb = K + (size_t)b * 65536 + h * 32;
  const float* Vb = V + (size_t)b * 65536 + h * 32;
  const float* Qb0 = Q + (size_t)b * 65536 + h * 32 + (size_t)l0 * 64;
  const float* Qb1 = Qb0 + 128 * 64;
  float qa[32], qb[32];
  #pragma unroll
  for (int i = 0; i < 8; ++i) {
    float4 v4 = ((const float4*)Qb0)[i];
    qa[4*i] = v4.x; qa[4*i+1] = v4.y; qa[4*i+2] = v4.z; qa[4*i+3] = v4.w;
    float4 w4 = ((const float4*)Qb1)[i];
    qb[4*i] = w4.x; qb[4*i+1] = w4.y; qb[4*i+2] = w4.z; qb[4*i+3] = w4.w;
  }
  float oa[32], ob[32];
  #pragma unroll
  for (int d = 0; d < 32; ++d) { oa[d] = 0.0f; ob[d] = 0.0f; }
  float ssa = 0.0f, ssb = 0.0f;
  for (int st = 0; st < nstage; ++st) {
    __syncthreads();
    int sb = s0 + st * 128;
    for (int i = tid; i < 1024; i += 128) {
      int r = i >> 3, d4 = i & 7;
      ((float4*)&Ks[r][0])[d4] = *(const float4*)(Kb + (size_t)(sb + r) * 64 + d4 * 4);
      ((float4*)&Vs[r][0])[d4] = *(const float4*)(Vb + (size_t)(sb + r) * 64 + d4 * 4);
    }
    __syncthreads();
    for (int s = 0; s < 128; s += 2) {
      const float4* kp0 = (const float4*)&Ks[s][0];
      const float4* kp1 = (const float4*)&Ks[s + 1][0];
      float a0 = 0, a1 = 0, a2 = 0, a3 = 0;
      float c0 = 0, c1 = 0, c2 = 0, c3 = 0;
      float e0 = 0, e1 = 0, e2 = 0, e3 = 0;
      float g0 = 0, g1 = 0, g2 = 0, g3 = 0;
      #pragma unroll
      for (int i = 0; i < 8; ++i) {
        float4 k0 = kp0[i], k1 = kp1[i];
        float qx = qa[4*i], qy = qa[4*i+1], qz = qa[4*i+2], qw = qa[4*i+3];
        a0 = fmaf(qx, k0.x, a0); a1 = fmaf(qy, k0.y, a1);
        a2 = fmaf(qz, k0.z, a2); a3 = fmaf(qw, k0.w, a3);
        c0 = fmaf(qx, k1.x, c0); c1 = fmaf(qy, k1.y, c1);
        c2 = fmaf(qz, k1.z, c2); c3 = fmaf(qw, k1.w, c3);
        qx = qb[4*i]; qy = qb[4*i+1]; qz = qb[4*i+2]; qw = qb[4*i+3];
        e0 = fmaf(qx, k0.x, e0); e1 = fmaf(qy, k0.y, e1);
        e2 = fmaf(qz, k0.z, e2); e3 = fmaf(qw, k0.w, e3);
        g0 = fmaf(qx, k1.x, g0); g1 = fmaf(qy, k1.y, g1);
        g2 = fmaf(qz, k1.z, g2); g3 = fmaf(qw, k1.w, g3);
      }
      float p0a = __expf(((a0 + a1) + (a2 + a3)) * SCALE_);
      float p1a = __expf(((c0 + c1) + (c2 + c3)) * SCALE_);
      float p0b = __expf(((e0 + e1) + (e2 + e3)) * SCALE_);
      float p1b = __expf(((g0 + g1) + (g2 + g3)) * SCALE_);
      ssa += p0a + p1a;
      ssb += p0b + p1b;
      const float4* vp0 = (const float4*)&Vs[s][0];
      const float4* vp1 = (const float4*)&Vs[s + 1][0];
      #pragma unroll
      for (int i = 0; i < 8; ++i) {
        float4 v0 = vp0[i], v1 = vp1[i];
        oa[4*i]   = fmaf(p0a, v0.x, fmaf(p1a, v1.x, oa[4*i]));
        oa[4*i+1] = fmaf(p0a, v0.y, fmaf(p1a, v1.y, oa[4*i+1]));
        oa[4*i+2] = fmaf(p0a, v0.z, fmaf(p1a, v1.z, oa[4*i+2]));
        oa[4*i+3] = fmaf(p0a, v0.w, fmaf(p1a, v1.w, oa[4*i+3]));
        ob[4*i]   = fmaf(p0b, v0.x, fmaf(p1b, v1.x, ob[4*i]));
        ob[4*i+1] = fmaf(p0b, v0.y, fmaf(p1b, v1.y, ob[4*i+1]));
        ob[4*i+2] = fmaf(p0b, v0.z, fmaf(p1b, v1.z, ob[4*i+2]));
        ob[4*i+3] = fmaf(p0b, v0.w, fmaf(p1b, v1.w, ob[4*i+3]));
      }
    }
  }
  float* pp = part + (((size_t)bh * gridDim.y + blockIdx.y) * 1024 + l0) * 36;
  #pragma unroll
  for (int i = 0; i < 8; ++i)
    ((float4*)pp)[i] = make_float4(oa[4*i], oa[4*i+1], oa[4*i+2], oa[4*i+3]);
  pp[32] = ssa;
  pp = part + (((size_t)bh * gridDim.y + blockIdx.y) * 1024 + l0 + 128) * 36;
  #pragma unroll
  for (int i = 0; i < 8; ++i)
    ((float4*)pp)[i] = make_float4(ob[4*i], ob[4*i+1], ob[4*i+2], ob[4*i+3]);
  pp[32] = ssb;
}

__global__ void attn_full_comb(const float* __restrict__ part, float* __restrict__ cbuf,
                               int nsplit) {
  int idx = blockIdx.x * 128 + threadIdx.x;
  int bh = idx >> 10, l = idx & 1023;
  int b = bh >> 1, h = bh & 1;
  float S = 0.0f;
  float o[32];
  #pragma unroll
  for (int d = 0; d < 32; ++d) o[d] = 0.0f;
  for (int j = 0; j < nsplit; ++j) {
    const float* pp = part + (((size_t)bh * nsplit + j) * 1024 + l) * 36;
    S += pp[32];
    #pragma unroll
    for (int i = 0; i < 8; ++i) {
      float4 v4 = ((const float4*)pp)[i];
      o[4*i] += v4.x; o[4*i+1] += v4.y; o[4*i+2] += v4.z; o[4*i+3] += v4.w;
    }
  }
  float inv = 1.0f / S;
  float* cc = cbuf + ((size_t)b * 1024 + l) * 352 + 0 + h * 32;
  #pragma unroll
  for (int d = 0; d < 32; ++d) cc[d] = o[d] * inv;
}

// ---------------------------------------------------------------------------
// log-sparse attention, single-pass no-max
// ---------------------------------------------------------------------------
__global__ void attn_log_kernel(const float* __restrict__ Q, const float* __restrict__ K,
                                const float* __restrict__ V, float* __restrict__ cbuf) {
  int idx = blockIdx.x * 128 + threadIdx.x;
  int bh = idx >> 10, l = idx & 1023;
  int b = bh >> 1, h = bh & 1;
  const float* Qb = Q + (size_t)b * 65536 + h * 32;
  const float* Kb = K + (size_t)b * 65536 + h * 32;
  const float* Vb = V + (size_t)b * 65536 + h * 32;
  float q[32];
  #pragma unroll
  for (int i = 0; i < 8; ++i) {
    float4 v4 = ((const float4*)(Qb + (size_t)l * 64))[i];
    q[4*i] = v4.x; q[4*i+1] = v4.y; q[4*i+2] = v4.z; q[4*i+3] = v4.w;
  }
  float o[32];
  #pragma unroll
  for (int d = 0; d < 32; ++d) o[d] = 0.0f;
  float ssum = 0.0f;
  #pragma unroll
  for (int j = 0; j < 11; ++j) {
    int off = (j == 0) ? 0 : (1 << (j - 1));
    if (off <= l) {
      int s = l - off;
      const float4* kp = (const float4*)(Kb + (size_t)s * 64);
      float a0 = 0, a1 = 0, a2 = 0, a3 = 0;
      #pragma unroll
      for (int i = 0; i < 8; ++i) {
        float4 kv = kp[i];
        a0 = fmaf(q[4*i], kv.x, a0);
        a1 = fmaf(q[4*i+1], kv.y, a1);
        a2 = fmaf(q[4*i+2], kv.z, a2);
        a3 = fmaf(q[4*i+3], kv.w, a3);
      }
      float p = __expf(((a0 + a1) + (a2 + a3)) * SCALE_);
      ssum += p;
      const float4* vp = (const float4*)(Vb + (size_t)s * 64);
      #pragma unroll
      for (int i = 0; i < 8; ++i) {
        float4 vv = vp[i];
        o[4*i]   = fmaf(p, vv.x, o[4*i]);
        o[4*i+1] = fmaf(p, vv.y, o[4*i+1]);
        o[4*i+2] = fmaf(p, vv.z, o[4*i+2]);
        o[4*i+3] = fmaf(p, vv.w, o[4*i+3]);
      }
    }
  }
  float inv = 1.0f / ssum;
  float* cc = cbuf + ((size_t)b * 1024 + l) * 352 + 64 + h * 32;
  #pragma unroll
  for (int d = 0; d < 32; ++d) cc[d] = o[d] * inv;
}

// local-window attention, single-pass no-max
__global__ void attn_loc_kernel(const float* __restrict__ Q, const float* __restrict__ K,
                                const float* __restrict__ V, float* __restrict__ cbuf) {
  int idx = blockIdx.x * 128 + threadIdx.x;
  int bh = idx >> 10, l = idx & 1023;
  int b = bh >> 1, h = bh & 1;
  const float* Qb = Q + (size_t)b * 65536 + h * 32;
  const float* Kb = K + (size_t)b * 65536 + h * 32;
  const float* Vb = V + (size_t)b * 65536 + h * 32;
  float q[32];
  #pragma unroll
  for (int i = 0; i < 8; ++i) {
    float4 v4 = ((const float4*)(Qb + (size_t)l * 64))[i];
    q[4*i] = v4.x; q[4*i+1] = v4.y; q[4*i+2] = v4.z; q[4*i+3] = v4.w;
  }
  float o[32];
  #pragma unroll
  for (int d = 0; d < 32; ++d) o[d] = 0.0f;
  float ssum = 0.0f;
  int jlo = (l >= 31) ? 0 : (31 - l);
  for (int j = jlo; j < 32; ++j) {
    int s = l - 31 + j;
    const float4* kp = (const float4*)(Kb + (size_t)s * 64);
    float a0 = 0, a1 = 0, a2 = 0, a3 = 0;
    #pragma unroll
    for (int i = 0; i < 8; ++i) {
      float4 kv = kp[i];
      a0 = fmaf(q[4*i], kv.x, a0);
      a1 = fmaf(q[4*i+1], kv.y, a1);
      a2 = fmaf(q[4*i+2], kv.z, a2);
      a3 = fmaf(q[4*i+3], kv.w, a3);
    }
    float p = __expf(((a0 + a1) + (a2 + a3)) * SCALE_);
    ssum += p;
    const float4* vp = (const float4*)(Vb + (size_t)s * 64);
    #pragma unroll
    for (int i = 0; i < 8; ++i) {
      float4 vv = vp[i];
      o[4*i]   = fmaf(p, vv.x, o[4*i]);
      o[4*i+1] = fmaf(p, vv.y, o[4*i+1]);
      o[4*i+2] = fmaf(p, vv.z, o[4*i+2]);
      o[4*i+3] = fmaf(p, vv.w, o[4*i+3]);
    }
  }
  float inv = 1.0f / ssum;
  float* cc = cbuf + ((size_t)b * 1024 + l) * 352 + 128 + h * 32;
  #pragma unroll
  for (int d = 0; d < 32; ++d) cc[d] = o[d] * inv;
}

// ---------------------------------------------------------------------------
// prob-sparse attention
// ---------------------------------------------------------------------------
__global__ void prob_m_kernel(const float* __restrict__ Q, const float* __restrict__ K,
                              const int* __restrict__ pidx, float* __restrict__ Mbuf) {
  int idx = blockIdx.x * 128 + threadIdx.x;
  int bh = idx >> 10, l = idx & 1023;
  int b = bh >> 1, h = bh & 1;
  const float* Qb = Q + (size_t)b * 65536 + h * 32;
  const float* Kb = K + (size_t)b * 65536 + h * 32;
  float q[32];
  #pragma unroll
  for (int i = 0; i < 8; ++i) {
    float4 v4 = ((const float4*)(Qb + (size_t)l * 64))[i];
    q[4*i] = v4.x; q[4*i+1] = v4.y; q[4*i+2] = v4.z; q[4*i+3] = v4.w;
  }
  float mx = -1e30f, sm = 0.0f;
  for (int u = 0; u < 35; ++u) {
    int ki = pidx[l * 35 + u];
    const float4* kp = (const float4*)(Kb + (size_t)ki * 64);
    float a0 = 0, a1 = 0, a2 = 0, a3 = 0;
    #pragma unroll
    for (int i = 0; i < 8; ++i) {
      float4 kv = kp[i];
      a0 = fmaf(q[4*i], kv.x, a0);
      a1 = fmaf(q[4*i+1], kv.y, a1);
      a2 = fmaf(q[4*i+2], kv.z, a2);
      a3 = fmaf(q[4*i+3], kv.w, a3);
    }
    float s = (a0 + a1) + (a2 + a3);
    mx = fmaxf(mx, s);
    sm += s;
  }
  Mbuf[(size_t)bh * 1024 + l] = mx - sm * (1.0f / 1024.0f);
}

// single-wave register-resident top-35 (no barriers)
__global__ void top35_kernel(const float* __restrict__ Mbuf, int* __restrict__ sel) {
  int bh = blockIdx.x;
  int lane = threadIdx.x;        // 64 threads
  float v[16];
  const float* Mb = Mbuf + (size_t)bh * 1024 + lane * 16;
  #pragma unroll
  for (int k = 0; k < 16; ++k) v[k] = Mb[k];
  for (int it = 0; it < 35; ++it) {
    float bv = -1e30f; int bi = 0;
    #pragma unroll
    for (int k = 0; k < 16; ++k)
      if (v[k] > bv) { bv = v[k]; bi = k; }
    int gidx = lane * 16 + bi;
    #pragma unroll
    for (int off = 32; off > 0; off >>= 1) {
      float ov = __shfl_down(bv, off, 64);
      int og = __shfl_down(gidx, off, 64);
      if (ov > bv || (ov == bv && og < gidx)) { bv = ov; gidx = og; }
    }
    gidx = __shfl(gidx, 0, 64);
    if (lane == 0) sel[bh * 35 + it] = gidx;
    if ((gidx >> 4) == lane) {
      int kk = gidx & 15;
      #pragma unroll
      for (int k = 0; k < 16; ++k)
        if (k == kk) v[k] = -1e30f;
    }
  }
}

__global__ void prob_fill_kernel(const float* __restrict__ V, float* __restrict__ cbuf) {
  __shared__ float red[256];
  __shared__ float vm[32];
  int bh = blockIdx.x, b = bh >> 1, h = bh & 1;
  int tid = threadIdx.x;
  int d = tid & 31, ch = tid >> 5;
  const float* Vb = V + (size_t)b * 65536 + h * 32;
  float s = 0.0f;
  for (int ss = ch * 128; ss < ch * 128 + 128; ++ss) s += Vb[(size_t)ss * 64 + d];
  red[tid] = s;
  __syncthreads();
  if (ch == 0) {
    float t = 0.0f;
    for (int c = 0; c < 8; ++c) t += red[c * 32 + d];
    vm[d] = t * (1.0f / 1024.0f);
  }
  __syncthreads();
  for (int i = tid; i < 1024 * 32; i += 256) {
    int l = i >> 5, dd = i & 31;
    cbuf[((size_t)b * 1024 + l) * 352 + 192 + h * 32 + dd] = vm[dd];
  }
}

__global__ void prob_part_kernel(const float* __restrict__ Q, const float* __restrict__ K,
                                 const float* __restrict__ V, const int* __restrict__ sel,
                                 float* __restrict__ ppart) {
  int bh = blockIdx.y, b = bh >> 1, h = bh & 1;
  int sc0 = blockIdx.x * 64;
  int u = threadIdx.x;
  int uu = (u < 35) ? u : 34;
  int l = sel[bh * 35 + uu];
  const float* Qb = Q + (size_t)b * 65536 + h * 32;
  const float* Kb = K + (size_t)b * 65536 + h * 32;
  const float* Vb = V + (size_t)b * 65536 + h * 32;
  float q[32];
  #pragma unroll
  for (int i = 0; i < 8; ++i) {
    float4 v4 = ((const float4*)(Qb + (size_t)l * 64))[i];
    q[4*i] = v4.x; q[4*i+1] = v4.y; q[4*i+2] = v4.z; q[4*i+3] = v4.w;
  }
  float o[32];
  #pragma unroll
  for (int dd = 0; dd < 32; ++dd) o[dd] = 0.0f;
  float ssum = 0.0f;
  for (int s = sc0; s < sc0 + 64; ++s) {
    const float4* kp = (const float4*)(Kb + (size_t)s * 64);
    float a0 = 0, a1 = 0, a2 = 0, a3 = 0;
    #pragma unroll
    for (int i = 0; i < 8; ++i) {
      float4 kv = kp[i];
      a0 = fmaf(q[4*i], kv.x, a0);
      a1 = fmaf(q[4*i+1], kv.y, a1);
      a2 = fmaf(q[4*i+2], kv.z, a2);
      a3 = fmaf(q[4*i+3], kv.w, a3);
    }
    float p = __expf(((a0 + a1) + (a2 + a3)) * SCALE_);
    ssum += p;
    const float4* vp = (const float4*)(Vb + (size_t)s * 64);
    #pragma unroll
    for (int i = 0; i < 8; ++i) {
      float4 vv = vp[i];
      o[4*i]   = fmaf(p, vv.x, o[4*i]);
      o[4*i+1] = fmaf(p, vv.y, o[4*i+1]);
      o[4*i+2] = fmaf(p, vv.z, o[4*i+2]);
      o[4*i+3] = fmaf(p, vv.w, o[4*i+3]);
    }
  }
  if (u < 35) {
    float* pp = ppart + (((size_t)bh * 16 + blockIdx.x) * 35 + u) * 36;
    #pragma unroll
    for (int i = 0; i < 8; ++i)
      ((float4*)pp)[i] = make_float4(o[4*i], o[4*i+1], o[4*i+2], o[4*i+3]);
    pp[32] = ssum;
  }
}

__global__ void prob_comb_kernel(const float* __restrict__ ppart, const int* __restrict__ sel,
                                 float* __restrict__ cbuf) {
  int t = blockIdx.x * 64 + threadIdx.x;
  if (t >= 32 * 35) return;
  int bh = t / 35, u = t % 35;
  int b = bh >> 1, h = bh & 1;
  int l = sel[bh * 35 + u];
  float S = 0.0f;
  float o[32];
  #pragma unroll
  for (int d = 0; d < 32; ++d) o[d] = 0.0f;
  for (int j = 0; j < 16; ++j) {
    const float* pp = ppart + (((size_t)bh * 16 + j) * 35 + u) * 36;
    S += pp[32];
    #pragma unroll
    for (int i = 0; i < 8; ++i) {
      float4 v4 = ((const float4*)pp)[i];
      o[4*i] += v4.x; o[4*i+1] += v4.y; o[4*i+2] += v4.z; o[4*i+3] += v4.w;
    }
  }
  float inv = 1.0f / S;
  float* cc = cbuf + ((size_t)b * 1024 + l) * 352 + 192 + h * 32;
  #pragma unroll
  for (int d = 0; d < 32; ++d) cc[d] = o[d] * inv;
}

// ---------------------------------------------------------------------------
// autocorrelation: mv[b,tau] = (1/64) sum_{c,t} K[b,c,t] * Q[b,c,(t+tau)%1024]
// 128 threads, 8 taus/thread, rolling 16-float q window, swizzled b128 reads.
// ---------------------------------------------------------------------------
__global__ void auto_mv_part(const float* __restrict__ Qa, const float* __restrict__ Ka,
                             float* __restrict__ part) {
  __shared__ float4 qs4[512];
  int c = blockIdx.x, b = blockIdx.y;
  int tid = threadIdx.x;         // 128
  const float* Qb = Qa + (size_t)b * 65536 + (size_t)c * 1024;
  const float* Kb = Ka + (size_t)b * 65536 + (size_t)c * 1024;
  const float4* Qb4 = (const float4*)Qb;
  for (int blk = tid; blk < 512; blk += 128) {
    int pb = blk ^ ((blk >> 3) & 7);
    qs4[pb] = Qb4[blk & 255];
  }
  __syncthreads();
  float acc[8];
  #pragma unroll
  for (int j = 0; j < 8; ++j) acc[j] = 0.0f;
  int base = 2 * tid;
  float4 v0, v1;
  {
    int b0 = base, b1 = base + 1;
    v0 = qs4[b0 ^ ((b0 >> 3) & 7)];
    v1 = qs4[b1 ^ ((b1 >> 3) & 7)];
  }
  for (int t = 0; t < 1024; t += 8) {
    int b2 = (t >> 2) + base + 2, b3 = b2 + 1;
    float4 v2 = qs4[b2 ^ ((b2 >> 3) & 7)];
    float4 v3 = qs4[b3 ^ ((b3 >> 3) & 7)];
    float4 k0 = *(const float4*)(Kb + t);
    float4 k1 = *(const float4*)(Kb + t + 4);
    float W[16] = {v0.x, v0.y, v0.z, v0.w, v1.x, v1.y, v1.z, v1.w,
                   v2.x, v2.y, v2.z, v2.w, v3.x, v3.y, v3.z, v3.w};
    float K8[8] = {k0.x, k0.y, k0.z, k0.w, k1.x, k1.y, k1.z, k1.w};
    #pragma unroll
    for (int j = 0; j < 8; ++j) {
      float a = acc[j];
      #pragma unroll
      for (int i = 0; i < 8; ++i) a = fmaf(K8[i], W[j + i], a);
      acc[j] = a;
    }
    v0 = v2; v1 = v3;
  }
  float* pp = &part[(((size_t)b * 64 + c) << 10) + tid * 8];
  *(float4*)pp = make_float4(acc[0], acc[1], acc[2], acc[3]);
  *(float4*)(pp + 4) = make_float4(acc[4], acc[5], acc[6], acc[7]);
}

__global__ void auto_mv_reduce(const float* __restrict__ part, float* __restrict__ mv) {
  int idx = blockIdx.x * 256 + threadIdx.x;
  int b = idx >> 10, tau = idx & 1023;
  float s = 0.0f;
  for (int c = 0; c < 64; ++c) s += part[(((size_t)b * 64 + c) << 10) + tau];
  mv[(size_t)b * 1024 + tau] = s * (1.0f / 64.0f);
}

// single-wave top-6 + per-batch softmax weights
__global__ void auto_top6_kernel(const float* __restrict__ mv, int* __restrict__ idx6,
                                 float* __restrict__ w6) {
  __shared__ int id6s[6];
  int lane = threadIdx.x;     // 64 threads
  float v[16];
  #pragma unroll
  for (int k = 0; k < 16; ++k) {
    int i = lane * 16 + k;
    float s = 0.0f;
    for (int b = 0; b < 16; ++b) s += mv[(size_t)b * 1024 + i];
    v[k] = s;
  }
  for (int it = 0; it < 6; ++it) {
    float bv = -1e30f; int bi = 0;
    #pragma unroll
    for (int k = 0; k < 16; ++k)
      if (v[k] > bv) { bv = v[k]; bi = k; }
    int gidx = lane * 16 + bi;
    #pragma unroll
    for (int off = 32; off > 0; off >>= 1) {
      float ov = __shfl_down(bv, off, 64);
      int og = __shfl_down(gidx, off, 64);
      if (ov > bv || (ov == bv && og < gidx)) { bv = ov; gidx = og; }
    }
    gidx = __shfl(gidx, 0, 64);
    if (lane == 0) { idx6[it] = gidx; id6s[it] = gidx; }
    if ((gidx >> 4) == lane) {
      int kk = gidx & 15;
      #pragma unroll
      for (int k = 0; k < 16; ++k)
        if (k == kk) v[k] = -1e30f;
    }
  }
  __syncthreads();
  if (lane < 16) {
    int b = lane;
    float vals[6]; float mx = -1e30f;
    #pragma unroll
    for (int j = 0; j < 6; ++j) { vals[j] = mv[(size_t)b * 1024 + id6s[j]]; mx = fmaxf(mx, vals[j]); }
    float s = 0.0f;
    #pragma unroll
    for (int j = 0; j < 6; ++j) { vals[j] = __expf(vals[j] - mx); s += vals[j]; }
    #pragma unroll
    for (int j = 0; j < 6; ++j) w6[b * 6 + j] = vals[j] / s;
  }
}

__global__ void auto_agg_kernel(const float* __restrict__ Va, const float* __restrict__ iq,
                                const float* __restrict__ wap, const float* __restrict__ bap,
                                const int* __restrict__ idx6, const float* __restrict__ w6,
                                float* __restrict__ ca) {
  __shared__ float aggs[16][64];
  __shared__ float w6s[6];
  __shared__ int id6[6];
  int b = blockIdx.y, t0 = blockIdx.x * 16;
  int tid = threadIdx.x;
  if (tid < 6) { w6s[tid] = w6[b * 6 + tid]; id6[tid] = idx6[tid]; }
  __syncthreads();
  const float* Vb = Va + (size_t)b * 65536;
  for (int i = tid; i < 1024; i += 256) {
    int tl = i >> 6, c = i & 63;
    int t = t0 + tl;
    float s = 0.0f;
    #pragma unroll
    for (int j = 0; j < 6; ++j)
      s += w6s[j] * Vb[(size_t)((t + id6[j]) & 1023) * 64 + c];
    aggs[tl][c] = s;
  }
  __syncthreads();
  int dm = tid & 127, tp = tid >> 7;
  float acc[8];
  #pragma unroll
  for (int r = 0; r < 8; ++r) {
    int t = t0 + tp * 8 + r;
    acc[r] = bap[dm] + iq[((size_t)b * 1024 + t) * 128 + dm];
  }
  for (int c = 0; c < 64; ++c) {
    float wv = wap[c * 128 + dm];
    #pragma unroll
    for (int r = 0; r < 8; ++r) acc[r] += aggs[tp * 8 + r][c] * wv;
  }
  #pragma unroll
  for (int r = 0; r < 8; ++r)
    ca[((size_t)b * 1024 + t0 + tp * 8 + r) * 128 + dm] = acc[r];
}

// moving-average detrend (k=25, edge-replicate, running window) + asize proj
__global__ void auto_ma_kernel(const float* __restrict__ ca, const float* __restrict__ was,
                               const float* __restrict__ bas, float* __restrict__ cbuf) {
  __shared__ float cas[40][128];
  __shared__ float diff[16][128];
  int b = blockIdx.y, t0 = blockIdx.x * 16;
  int tid = threadIdx.x;
  for (int i = tid; i < 40 * 128; i += 256) {
    int r = i >> 7, d = i & 127;
    int t = t0 - 12 + r;
    t = (t < 0) ? 0 : ((t > 1023) ? 1023 : t);
    cas[r][d] = ca[((size_t)b * 1024 + t) * 128 + d];
  }
  __syncthreads();
  int d = tid & 127, hf = tid >> 7;
  int tl0 = hf * 8;
  float s = 0.0f;
  #pragma unroll
  for (int w = 0; w < 25; ++w) s += cas[tl0 + w][d];
  #pragma unroll
  for (int k = 0; k < 8; ++k) {
    int tl = tl0 + k;
    diff[tl][d] = cas[tl + 12][d] - s * (1.0f / 25.0f);
    if (k < 7) s += cas[tl + 25][d] - cas[tl][d];
  }
  __syncthreads();
  int j = tid & 63, tq = tid >> 6;
  float acc[4];
  #pragma unroll
  for (int r = 0; r < 4; ++r) acc[r] = bas[j];
  for (int dd = 0; dd < 128; ++dd) {
    float wv = was[dd * 64 + j];
    #pragma unroll
    for (int r = 0; r < 4; ++r) acc[r] += diff[tq * 4 + r][dd] * wv;
  }
  #pragma unroll
  for (int r = 0; r < 4; ++r)
    cbuf[((size_t)b * 1024 + t0 + tq * 4 + r) * 352 + 288 + j] = acc[r];
}

// ---------------------------------------------------------------------------
// FFT branch: Y = X @ wfft, then cf_proj[f] = sum_t cos(2pi f t/1024) Y[t]
// symmetry: cf[1024-f] == cf[f]; f=512 (alternating sum) fused into block x=0
// ---------------------------------------------------------------------------
__global__ void fftY_kernel(const float* __restrict__ x, const float* __restrict__ wfft,
                            float* __restrict__ Y) {
  __shared__ float xs[64][128];
  __shared__ float ws[32][129];
  int b = blockIdx.y, t0 = blockIdx.x * 64;
  int tid = threadIdx.x;
  for (int i = tid; i < 64 * 128; i += 256) {
    int r = i >> 7, d = i & 127;
    xs[r][d] = x[(size_t)b * 131072 + (size_t)(t0 + r) * 128 + d];
  }
  for (int i = tid; i < 4096; i += 256) {
    int d = i >> 5, j = i & 31;
    ws[j][d] = wfft[i];
  }
  __syncthreads();
  int j = tid & 31, tt0 = (tid >> 5) * 8;
  float acc[8];
  #pragma unroll
  for (int r = 0; r < 8; ++r) acc[r] = 0.0f;
  for (int d0 = 0; d0 < 128; d0 += 4) {
    float w0 = ws[j][d0], w1 = ws[j][d0 + 1], w2 = ws[j][d0 + 2], w3 = ws[j][d0 + 3];
    #pragma unroll
    for (int r = 0; r < 8; ++r) {
      float4 xv = *(const float4*)&xs[tt0 + r][d0];
      float a = acc[r];
      a = fmaf(w0, xv.x, a);
      a = fmaf(w1, xv.y, a);
      a = fmaf(w2, xv.z, a);
      a = fmaf(w3, xv.w, a);
      acc[r] = a;
    }
  }
  #pragma unroll
  for (int r = 0; r < 8; ++r)
    Y[((size_t)b * 1024 + t0 + tt0 + r) * 32 + j] = acc[r];
}

__global__ void fftT_kernel(const float* __restrict__ Y, const float* __restrict__ bfft,
                            float* __restrict__ cbuf) {
  __shared__ float ys[256 * 32];
  __shared__ float altred[8][32];
  int b = blockIdx.y, fbase = blockIdx.x * 64;
  int tid = threadIdx.x;
  int fi = tid & 31, jg = tid >> 5, j0 = jg * 4;
  int f0 = fbase + fi * 2;
  const float TWO_PI_N = 6.283185307179586476925f / 1024.0f;
  float ca0, sa0, ca1, sa1;
  sincosf(TWO_PI_N * (float)f0, &sa0, &ca0);
  sincosf(TWO_PI_N * (float)(f0 + 1), &sa1, &ca1);
  float cr0 = 1.0f, ci0 = 0.0f, cr1 = 1.0f, ci1 = 0.0f;
  float4 acc0 = make_float4(0.f, 0.f, 0.f, 0.f);
  float4 acc1 = make_float4(0.f, 0.f, 0.f, 0.f);
  bool do512 = (blockIdx.x == 0);
  int aj = tid & 31, arow = tid >> 5;
  float alt = 0.0f;
  for (int chk = 0; chk < 4; ++chk) {
    __syncthreads();
    const float4* Yp = (const float4*)(Y + ((size_t)b * 1024 + chk * 256) * 32);
    for (int i = tid; i < 2048; i += 256) ((float4*)ys)[i] = Yp[i];
    __syncthreads();
    for (int tl = 0; tl < 256; ++tl) {
      float4 yv = *(const float4*)&ys[tl * 32 + j0];
      acc0.x = fmaf(cr0, yv.x, acc0.x);
      acc0.y = fmaf(cr0, yv.y, acc0.y);
      acc0.z = fmaf(cr0, yv.z, acc0.z);
      acc0.w = fmaf(cr0, yv.w, acc0.w);
      acc1.x = fmaf(cr1, yv.x, acc1.x);
      acc1.y = fmaf(cr1, yv.y, acc1.y);
      acc1.z = fmaf(cr1, yv.z, acc1.z);
      acc1.w = fmaf(cr1, yv.w, acc1.w);
      float nr0 = cr0 * ca0 - ci0 * sa0;
      float ni0 = cr0 * sa0 + ci0 * ca0;
      cr0 = nr0; ci0 = ni0;
      float nr1 = cr1 * ca1 - ci1 * sa1;
      float ni1 = cr1 * sa1 + ci1 * ca1;
      cr1 = nr1; ci1 = ni1;
    }
    if (do512) {
      int tb = arow * 32;
      #pragma unroll 8
      for (int k = 0; k < 32; ++k) {
        float y = ys[(tb + k) * 32 + aj];
        alt += ((tb + k) & 1) ? -y : y;
      }
    }
  }
  float b0 = bfft[j0], b1 = bfft[j0 + 1], b2 = bfft[j0 + 2], b3 = bfft[j0 + 3];
  float* cc0 = cbuf + ((size_t)b * 1024 + f0) * 352 + 256 + j0;
  cc0[0] = acc0.x + b0; cc0[1] = acc0.y + b1; cc0[2] = acc0.z + b2; cc0[3] = acc0.w + b3;
  float* cc1 = cbuf + ((size_t)b * 1024 + f0 + 1) * 352 + 256 + j0;
  cc1[0] = acc1.x + b0; cc1[1] = acc1.y + b1; cc1[2] = acc1.z + b2; cc1[3] = acc1.w + b3;
  if (f0 > 0) {
    float* cm0 = cbuf + ((size_t)b * 1024 + (1024 - f0)) * 352 + 256 + j0;
    cm0[0] = acc0.x + b0; cm0[1] = acc0.y + b1; cm0[2] = acc0.z + b2; cm0[3] = acc0.w + b3;
  }
  {
    float* cm1 = cbuf + ((size_t)b * 1024 + (1024 - f0 - 1)) * 352 + 256 + j0;
    cm1[0] = acc1.x + b0; cm1[1] = acc1.y + b1; cm1[2] = acc1.z + b2; cm1[3] = acc1.w + b3;
  }
  if (do512) {
    altred[arow][aj] = alt;
    __syncthreads();
    if (tid < 32) {
      float s = 0.0f;
      #pragma unroll
      for (int r = 0; r < 8; ++r) s += altred[r][tid];
      cbuf[((size_t)b * 1024 + 512) * 352 + 256 + tid] = s + bfft[tid];
    }
  }
}

// ---------------------------------------------------------------------------
// final: out = cbuf @ w_fc + iq, then layernorm over DM
// ---------------------------------------------------------------------------
__global__ void fc_ln_kernel(const float* __restrict__ cbuf, const float* __restrict__ wfc,
                             const float* __restrict__ iq, float* __restrict__ out) {
  __shared__ float cs[16][352];
  __shared__ float os[16][128];
  int b = blockIdx.y, t0 = blockIdx.x * 16;
  int tid = threadIdx.x;
  for (int i = tid; i < 16 * 352; i += 256) {
    int r = i / 352, col = i % 352;
    cs[r][col] = cbuf[((size_t)b * 1024 + t0 + r) * 352 + col];
  }
  __syncthreads();
  int j = tid & 127, half = tid >> 7;
  float acc[8];
  #pragma unroll
  for (int k = 0; k < 8; ++k)
    acc[k] = iq[((size_t)b * 1024 + t0 + half * 8 + k) * 128 + j];
  for (int i = 0; i < 352; ++i) {
    float wv = wfc[i * 128 + j];
    #pragma unroll
    for (int k = 0; k < 8; ++k) acc[k] += cs[half * 8 + k][i] * wv;
  }
  #pragma unroll
  for (int k = 0; k < 8; ++k) os[half * 8 + k][j] = acc[k];
  __syncthreads();
  int wid = tid >> 6, lane = tid & 63;
  for (int rr = 0; rr < 4; ++rr) {
    int r = wid * 4 + rr;
    float x0 = os[r][lane], x1 = os[r][lane + 64];
    float s1 = x0 + x1;
    float s2 = x0 * x0 + x1 * x1;
    #pragma unroll
    for (int k = 32; k > 0; k >>= 1) {
      s1 += __shfl_xor(s1, k, 64);
      s2 += __shfl_xor(s2, k, 64);
    }
    float mean = s1 * (1.0f / 128.0f);
    float var = s2 * (1.0f / 128.0f) - mean * mean;
    float rstd = 1.0f / sqrtf(var + 1e-5f);
    float* op = out + ((size_t)b * 1024 + t0 + r) * 128;
    op[lane] = (x0 - mean) * rstd;
    op[lane + 64] = (x1 - mean) * rstd;
  }
}

// ---------------------------------------------------------------------------
extern "C" void kernel_launch(void* const* d_in, const int* in_sizes, int n_in,
                              void* d_out, int out_size, void* d_ws, size_t ws_size,
                              hipStream_t stream) {
  (void)in_sizes; (void)n_in; (void)out_size;
  const float* inQ = (const float*)d_in[0];
  const float* inK = (const float*)d_in[1];
  const float* inV = (const float*)d_in[2];
  const float *wq[5], *bq[5], *wk[5], *bk[5], *wv[5], *bv[5];
  for (int br = 0; br < 5; ++br) {
    wq[br] = (const float*)d_in[3 + br * 6 + 0];
    bq[br] = (const float*)d_in[3 + br * 6 + 1];
    wk[br] = (const float*)d_in[3 + br * 6 + 2];
    bk[br] = (const float*)d_in[3 + br * 6 + 3];
    wv[br] = (const float*)d_in[3 + br * 6 + 4];
    bv[br] = (const float*)d_in[3 + br * 6 + 5];
  }
  const float* wfft = (const float*)d_in[33];
  const float* bfft = (const float*)d_in[34];
  const float* wap  = (const float*)d_in[35];
  const float* bap  = (const float*)d_in[36];
  const float* was  = (const float*)d_in[37];
  const float* bas  = (const float*)d_in[38];
  const float* wfc  = (const float*)d_in[39];
  float* out = (float*)d_out;

  bool mega = ws_size >= (size_t)128 * 1024 * 1024;
  int nsplit = (ws_size >= (size_t)76 * 1024 * 1024) ? 8 : 4;
  int stile = 1024 / nsplit;
  int nstage = stile / 128;

  char* wsb = (char*)d_ws;
  size_t off = 0;
  auto alloc = [&](size_t bytes) -> void* {
    void* p = wsb + off;
    off += (bytes + 255) & ~(size_t)255;
    return p;
  };
  int*   pidx = (int*)  alloc((size_t)35840 * 4);
  float* qkvall = (float*)alloc((size_t)(mega ? 15 : 3) * 1048576 * 4);
  float* cbuf = (float*)alloc((size_t)16 * 1024 * 352 * 4);
  float* fpart = (float*)alloc((size_t)32 * nsplit * 1024 * 36 * 4);
  float* Mbuf = (float*)alloc((size_t)32 * 1024 * 4);
  int*   sel  = (int*)  alloc((size_t)32 * 35 * 4);
  float* mvb  = (float*)alloc((size_t)16 * 1024 * 4);
  int*   idx6 = (int*)  alloc(64);
  float* w6   = (float*)alloc((size_t)16 * 6 * 4);
  // aliases into fpart (timeline-disjoint):
  float* ppart = fpart;                                              // prob partials
  float* cab   = fpart;                                              // auto ca (8MiB)
  float* mpart = (float*)((char*)fpart + (size_t)8 * 1024 * 1024);   // corr partials (4MiB)
  float* Ybuf  = (float*)((char*)fpart + (size_t)12 * 1024 * 1024);  // fft Y (2MiB)

  mt_kernel<<<1, 256, 0, stream>>>(pidx);

  if (mega) {
    ConvArgs ca;
    ca.x[0] = inQ; ca.x[1] = inK; ca.x[2] = inV;
    for (int br = 0; br < 5; ++br) {
      ca.w[br * 3 + 0] = wq[br]; ca.bia[br * 3 + 0] = bq[br];
      ca.w[br * 3 + 1] = wk[br]; ca.bia[br * 3 + 1] = bk[br];
      ca.w[br * 3 + 2] = wv[br]; ca.bia[br * 3 + 2] = bv[br];
    }
    ca.outbase = qkvall;
    conv3_mega<<<dim3(8, 16, 10), 256, 0, stream>>>(ca);
    conv1_mega<<<dim3(16, 16, 5), 256, 0, stream>>>(ca);
  }
  auto bufs = [&](int br, float*& qb, float*& kb, float*& vb) {
    int bi = mega ? br : 0;
    qb = qkvall + (size_t)(bi * 3 + 0) * 1048576;
    kb = qkvall + (size_t)(bi * 3 + 1) * 1048576;
    vb = qkvall + (size_t)(bi * 3 + 2) * 1048576;
  };
  auto conv_branch = [&](int br, float* qb, float* kb, float* vb) {
    if (!mega)
      qkv_conv_kernel<<<dim3(16, 16, 3), 256, 0, stream>>>(
          inQ, inK, inV, wq[br], bq[br], wk[br], bk[br], wv[br], bv[br], qb, kb, vb);
  };
  float *qb, *kb, *vb;

  // branch 0: full attention
  bufs(0, qb, kb, vb);
  conv_branch(0, qb, kb, vb);
  attn_full_part<<<dim3(4, nsplit, 32), 128, 0, stream>>>(qb, kb, vb, fpart, stile, nstage);
  attn_full_comb<<<256, 128, 0, stream>>>(fpart, cbuf, nsplit);

  // branch 1: log-sparse
  bufs(1, qb, kb, vb);
  conv_branch(1, qb, kb, vb);
  attn_log_kernel<<<256, 128, 0, stream>>>(qb, kb, vb, cbuf);

  // branch 2: local window
  bufs(2, qb, kb, vb);
  conv_branch(2, qb, kb, vb);
  attn_loc_kernel<<<256, 128, 0, stream>>>(qb, kb, vb, cbuf);

  // branch 3: prob-sparse
  bufs(3, qb, kb, vb);
  conv_branch(3, qb, kb, vb);
  prob_m_kernel<<<256, 128, 0, stream>>>(qb, kb, pidx, Mbuf);
  top35_kernel<<<32, 64, 0, stream>>>(Mbuf, sel);
  prob_fill_kernel<<<32, 256, 0, stream>>>(vb, cbuf);
  prob_part_kernel<<<dim3(16, 32), 64, 0, stream>>>(qb, kb, vb, sel, ppart);
  prob_comb_kernel<<<18, 64, 0, stream>>>(ppart, sel, cbuf);

  // branch 4: autocorrelation
  bufs(4, qb, kb, vb);
  conv_branch(4, qb, kb, vb);
  auto_mv_part<<<dim3(64, 16), 128, 0, stream>>>(qb, kb, mpart);
  auto_mv_reduce<<<64, 256, 0, stream>>>(mpart, mvb);
  auto_top6_kernel<<<1, 64, 0, stream>>>(mvb, idx6, w6);
  auto_agg_kernel<<<dim3(64, 16), 256, 0, stream>>>(vb, inQ, wap, bap, idx6, w6, cab);
  auto_ma_kernel<<<dim3(64, 16), 256, 0, stream>>>(cab, was, bas, cbuf);

  // FFT branch (mirror symmetry; f=512 fused into fftT block x=0)
  fftY_kernel<<<dim3(16, 16), 256, 0, stream>>>(inQ, wfft, Ybuf);
  fftT_kernel<<<dim3(8, 16), 256, 0, stream>>>(Ybuf, bfft, cbuf);

  // final projection + layernorm
  fc_ln_kernel<<<dim3(64, 16), 256, 0, stream>>>(cbuf, wfc, inQ, out);
}

// Round 19
// 666.011 us; speedup vs baseline: 1.0100x; 1.0100x over previous
//
#include <hip/hip_runtime.h>
#include <hip/hip_bf16.h>
#include <math.h>

#define B_   16
#define L_   1024
#define SCALE_ 0.17677669529663687f   // 1/sqrt(32)

// ---------------------------------------------------------------------------
// MT19937 -> PROB_IDX (35840 draws of genrand_int32() & 1023, seed 0)
// ---------------------------------------------------------------------------
__global__ void mt_kernel(int* __restrict__ pidx) {
  __shared__ unsigned int mt[624];
  int tid = threadIdx.x;   // 256
  if (tid == 0) {
    unsigned int s = 0u;
    for (int i = 0; i < 624; ++i) {
      mt[i] = s;
      s = 1812433253u * (s ^ (s >> 30)) + (unsigned)(i + 1);
    }
  }
  __syncthreads();
  const unsigned int HI = 0x80000000u, LO = 0x7fffffffu, MM = 0x9908b0dfu;
  for (int blk = 0; blk < 58; ++blk) {
    unsigned int n0 = 0, n1 = 0, n2 = 0, old623 = 0;
    bool a0 = tid < 227, a2 = tid < 169;
    if (a0) {
      unsigned int y0 = (mt[tid] & HI) | (mt[tid + 1] & LO);
      n0 = mt[tid + 397] ^ (y0 >> 1) ^ ((y0 & 1u) ? MM : 0u);
      unsigned int y1 = (mt[tid + 227] & HI) | (mt[tid + 228] & LO);
      n1 = n0 ^ (y1 >> 1) ^ ((y1 & 1u) ? MM : 0u);
      if (a2) {
        unsigned int y2 = (mt[tid + 454] & HI) | (mt[tid + 455] & LO);
        n2 = n1 ^ (y2 >> 1) ^ ((y2 & 1u) ? MM : 0u);
      }
      if (tid == 169) old623 = mt[623];
    }
    __syncthreads();
    if (a0) {
      mt[tid] = n0;
      mt[tid + 227] = n1;
      if (a2) mt[tid + 454] = n2;
    }
    __syncthreads();
    if (tid == 169) {
      unsigned int y = (old623 & HI) | (mt[0] & LO);
      mt[623] = n1 ^ (y >> 1) ^ ((y & 1u) ? MM : 0u);
    }
    __syncthreads();
    for (int i = tid; i < 624; i += 256) {
      int g = blk * 624 + i;
      if (g < 35840) {
        unsigned int y = mt[i];
        y ^= y >> 11;
        y ^= (y << 7) & 0x9d2c5680u;
        y ^= (y << 15) & 0xefc60000u;
        y ^= y >> 18;
        pidx[g] = (int)(y & 1023u);
      }
    }
  }
}

// ---------------------------------------------------------------------------
// fp32 conv body (fallback path + conv1 slices). 2 ch x 8 t per thread.
// OUTPUT CHANNEL-MAJOR: out[b, c*1024 + t]. Blocks cover 64 t.
// ---------------------------------------------------------------------------
__device__ __forceinline__ void conv_body(const float* __restrict__ x,
                                          const float* __restrict__ w,
                                          const float* __restrict__ bias,
                                          float* __restrict__ out,
                                          float* smem, int b, int t0, int tid, int is1) {
  int cp = tid & 31;          // channels cp and cp+32
  int tg = tid >> 5;          // 0..7
  int tt0 = tg * 8;           // 8 t per thread
  float acc0[8], acc1[8];
  float b0v = bias[cp], b1v = bias[cp + 32];
  #pragma unroll
  for (int j = 0; j < 8; ++j) { acc0[j] = b0v; acc1[j] = b1v; }
  if (!is1) {
    float* xs = smem;            // [66][128]
    float* ws = smem + 8448;     // [64][52]
    for (int i = tid; i < 66 * 128; i += 256) {
      int r = i >> 7, d = i & 127;
      int t = t0 - 2 + r;
      xs[r * 128 + d] = (t >= 0) ? x[(size_t)b * 131072 + (size_t)t * 128 + d] : 0.0f;
    }
    for (int dc = 0; dc < 128; dc += 16) {
      __syncthreads();
      {
        int row = tid >> 2, sub = tid & 3;
        const float* wsrc = w + row * 384 + dc * 3 + sub * 12;
        float* wdst = ws + row * 52 + sub * 12;
        #pragma unroll
        for (int k = 0; k < 12; ++k) wdst[k] = wsrc[k];
      }
      __syncthreads();
      #pragma unroll
      for (int dl = 0; dl < 16; dl += 4) {
        int d0 = dc + dl;
        float4 xr[10];
        #pragma unroll
        for (int r = 0; r < 10; ++r) xr[r] = *(const float4*)&xs[(tt0 + r) * 128 + d0];
        float4 wa0 = *(const float4*)&ws[cp * 52 + dl * 3];
        float4 wa1 = *(const float4*)&ws[cp * 52 + dl * 3 + 4];
        float4 wa2 = *(const float4*)&ws[cp * 52 + dl * 3 + 8];
        float4 wb0 = *(const float4*)&ws[(cp + 32) * 52 + dl * 3];
        float4 wb1 = *(const float4*)&ws[(cp + 32) * 52 + dl * 3 + 4];
        float4 wb2 = *(const float4*)&ws[(cp + 32) * 52 + dl * 3 + 8];
        float w0r[12] = {wa0.x, wa0.y, wa0.z, wa0.w, wa1.x, wa1.y, wa1.z, wa1.w,
                         wa2.x, wa2.y, wa2.z, wa2.w};
        float w1r[12] = {wb0.x, wb0.y, wb0.z, wb0.w, wb1.x, wb1.y, wb1.z, wb1.w,
                         wb2.x, wb2.y, wb2.z, wb2.w};
        #pragma unroll
        for (int j = 0; j < 8; ++j) {
          float a0 = acc0[j], a1 = acc1[j];
          #pragma unroll
          for (int k = 0; k < 3; ++k) {
            float4 xv = xr[j + k];
            a0 = fmaf(w0r[0 + k], xv.x, a0);
            a0 = fmaf(w0r[3 + k], xv.y, a0);
            a0 = fmaf(w0r[6 + k], xv.z, a0);
            a0 = fmaf(w0r[9 + k], xv.w, a0);
            a1 = fmaf(w1r[0 + k], xv.x, a1);
            a1 = fmaf(w1r[3 + k], xv.y, a1);
            a1 = fmaf(w1r[6 + k], xv.z, a1);
            a1 = fmaf(w1r[9 + k], xv.w, a1);
          }
          acc0[j] = a0; acc1[j] = a1;
        }
      }
    }
  } else {
    float* xs = smem;            // [64][128]
    float* ws = smem + 8192;     // [64][36]
    for (int i = tid; i < 64 * 128; i += 256) {
      int r = i >> 7, d = i & 127;
      xs[r * 128 + d] = x[(size_t)b * 131072 + (size_t)(t0 + r) * 128 + d];
    }
    for (int dc = 0; dc < 128; dc += 32) {
      __syncthreads();
      {
        int row = tid >> 2, sub = tid & 3;
        const float* wsrc = w + row * 128 + dc + sub * 8;
        float* wdst = ws + row * 36 + sub * 8;
        #pragma unroll
        for (int k = 0; k < 8; ++k) wdst[k] = wsrc[k];
      }
      __syncthreads();
      #pragma unroll
      for (int dl = 0; dl < 32; dl += 4) {
        int d0 = dc + dl;
        float4 wv0 = *(const float4*)&ws[cp * 36 + dl];
        float4 wv1 = *(const float4*)&ws[(cp + 32) * 36 + dl];
        #pragma unroll
        for (int j = 0; j < 8; ++j) {
          float4 xv = *(const float4*)&xs[(tt0 + j) * 128 + d0];
          float a0 = acc0[j], a1 = acc1[j];
          a0 = fmaf(wv0.x, xv.x, a0);
          a0 = fmaf(wv0.y, xv.y, a0);
          a0 = fmaf(wv0.z, xv.z, a0);
          a0 = fmaf(wv0.w, xv.w, a0);
          a1 = fmaf(wv1.x, xv.x, a1);
          a1 = fmaf(wv1.y, xv.y, a1);
          a1 = fmaf(wv1.z, xv.z, a1);
          a1 = fmaf(wv1.w, xv.w, a1);
          acc0[j] = a0; acc1[j] = a1;
        }
      }
    }
  }
  float* op0 = out + (size_t)b * 65536 + (size_t)cp * 1024 + t0 + tt0;
  float* op1 = out + (size_t)b * 65536 + (size_t)(cp + 32) * 1024 + t0 + tt0;
  *(float4*)op0 = make_float4(acc0[0], acc0[1], acc0[2], acc0[3]);
  *(float4*)(op0 + 4) = make_float4(acc0[4], acc0[5], acc0[6], acc0[7]);
  *(float4*)op1 = make_float4(acc1[0], acc1[1], acc1[2], acc1[3]);
  *(float4*)(op1 + 4) = make_float4(acc1[4], acc1[5], acc1[6], acc1[7]);
}

// per-branch merged QKV conv (fallback path). z=0:Qconv3 z=1:Kconv3 z=2:Vconv1
__global__ __launch_bounds__(256, 3)
void qkv_conv_kernel(const float* __restrict__ xq, const float* __restrict__ xk,
                     const float* __restrict__ xv,
                     const float* __restrict__ wq, const float* __restrict__ bq,
                     const float* __restrict__ wk, const float* __restrict__ bk,
                     const float* __restrict__ wv, const float* __restrict__ bv,
                     float* __restrict__ qo, float* __restrict__ ko,
                     float* __restrict__ vo) {
  __shared__ float smem[11776];
  int which = blockIdx.z;
  const float* x = (which == 0) ? xq : (which == 1) ? xk : xv;
  const float* w = (which == 0) ? wq : (which == 1) ? wk : wv;
  const float* bias = (which == 0) ? bq : (which == 1) ? bk : bv;
  float* out = (which == 0) ? qo : (which == 1) ? ko : vo;
  conv_body(x, w, bias, out, smem, blockIdx.y, blockIdx.x * 64, threadIdx.x, which == 2);
}

struct ConvArgs {
  const float* x[3];
  const float* w[15];
  const float* bia[15];
  float* outbase;   // [slice][16*65536]
};

// conv1 slices (mega path): z in {2,5,8,11,14}
__global__ __launch_bounds__(256, 3)
void conv1_mega(ConvArgs a) {
  __shared__ float smem[11776];
  const int zmap[5] = {2, 5, 8, 11, 14};
  int z = zmap[blockIdx.z];
  float* out = a.outbase + (size_t)z * 1048576;
  conv_body(a.x[2], a.w[z], a.bia[z], out, smem, blockIdx.y, blockIdx.x * 64,
            threadIdx.x, 1);
}

// ---------------------------------------------------------------------------
// conv3 slices (mega path): 4 ch x 8 t per thread, blocks cover 128 t.
// x staged per-16-d chunk (xs[130][16]); weights staged [64][52] as before.
// Per-channel accumulation order identical to conv_body -> bit-identical out.
// LDS: 130*16*4 + 64*52*4 = 8320 + 13312 = 21632 B
// ---------------------------------------------------------------------------
__global__ __launch_bounds__(256, 3)
void conv3_mega(ConvArgs a) {
  __shared__ float xs[130 * 16];
  __shared__ float ws[64 * 52];
  const int zmap[10] = {0, 1, 3, 4, 6, 7, 9, 10, 12, 13};
  int z = zmap[blockIdx.z];
  int which = z % 3;            // 0 or 1
  const float* x = a.x[which];
  const float* w = a.w[z];
  const float* bias = a.bia[z];
  float* out = a.outbase + (size_t)z * 1048576;
  int b = blockIdx.y, t0 = blockIdx.x * 128;
  int tid = threadIdx.x;
  int cg = tid & 15;            // channels cg, cg+16, cg+32, cg+48
  int tg = tid >> 4;            // 0..15
  int tt0 = tg * 8;
  int c0 = cg, c1 = cg + 16, c2 = cg + 32, c3 = cg + 48;
  float acc0[8], acc1[8], acc2[8], acc3[8];
  {
    float b0 = bias[c0], b1 = bias[c1], b2 = bias[c2], b3 = bias[c3];
    #pragma unroll
    for (int j = 0; j < 8; ++j) { acc0[j] = b0; acc1[j] = b1; acc2[j] = b2; acc3[j] = b3; }
  }
  for (int dc = 0; dc < 128; dc += 16) {
    __syncthreads();
    // stage weights: 64 ch x 48 floats for this d-chunk
    {
      int row = tid >> 2, sub = tid & 3;
      const float* wsrc = w + row * 384 + dc * 3 + sub * 12;
      float* wdst = ws + row * 52 + sub * 12;
      #pragma unroll
      for (int k = 0; k < 12; ++k) wdst[k] = wsrc[k];
    }
    // stage x chunk: rows t0-2 .. t0+127, d in [dc, dc+16)
    for (int i = tid; i < 520; i += 256) {
      int row = i >> 2, db = i & 3;
      int t = t0 - 2 + row;
      float4 v = make_float4(0.f, 0.f, 0.f, 0.f);
      if (t >= 0) v = *(const float4*)(x + (size_t)b * 131072 + (size_t)t * 128 + dc + db * 4);
      *(float4*)&xs[row * 16 + db * 4] = v;
    }
    __syncthreads();
    #pragma unroll
    for (int dl = 0; dl < 16; dl += 4) {
      float4 xr[10];
      #pragma unroll
      for (int r = 0; r < 10; ++r) xr[r] = *(const float4*)&xs[(tt0 + r) * 16 + dl];
      float4 p0 = *(const float4*)&ws[c0 * 52 + dl * 3];
      float4 p1 = *(const float4*)&ws[c0 * 52 + dl * 3 + 4];
      float4 p2 = *(const float4*)&ws[c0 * 52 + dl * 3 + 8];
      float w0r[12] = {p0.x, p0.y, p0.z, p0.w, p1.x, p1.y, p1.z, p1.w, p2.x, p2.y, p2.z, p2.w};
      p0 = *(const float4*)&ws[c1 * 52 + dl * 3];
      p1 = *(const float4*)&ws[c1 * 52 + dl * 3 + 4];
      p2 = *(const float4*)&ws[c1 * 52 + dl * 3 + 8];
      float w1r[12] = {p0.x, p0.y, p0.z, p0.w, p1.x, p1.y, p1.z, p1.w, p2.x, p2.y, p2.z, p2.w};
      p0 = *(const float4*)&ws[c2 * 52 + dl * 3];
      p1 = *(const float4*)&ws[c2 * 52 + dl * 3 + 4];
      p2 = *(const float4*)&ws[c2 * 52 + dl * 3 + 8];
      float w2r[12] = {p0.x, p0.y, p0.z, p0.w, p1.x, p1.y, p1.z, p1.w, p2.x, p2.y, p2.z, p2.w};
      p0 = *(const float4*)&ws[c3 * 52 + dl * 3];
      p1 = *(const float4*)&ws[c3 * 52 + dl * 3 + 4];
      p2 = *(const float4*)&ws[c3 * 52 + dl * 3 + 8];
      float w3r[12] = {p0.x, p0.y, p0.z, p0.w, p1.x, p1.y, p1.z, p1.w, p2.x, p2.y, p2.z, p2.w};
      #pragma unroll
      for (int j = 0; j < 8; ++j) {
        float a0 = acc0[j], a1 = acc1[j], a2 = acc2[j], a3 = acc3[j];
        #pragma unroll
        for (int k = 0; k < 3; ++k) {
          float4 xv = xr[j + k];
          a0 = fmaf(w0r[0 + k], xv.x, a0);
          a0 = fmaf(w0r[3 + k], xv.y, a0);
          a0 = fmaf(w0r[6 + k], xv.z, a0);
          a0 = fmaf(w0r[9 + k], xv.w, a0);
          a1 = fmaf(w1r[0 + k], xv.x, a1);
          a1 = fmaf(w1r[3 + k], xv.y, a1);
          a1 = fmaf(w1r[6 + k], xv.z, a1);
          a1 = fmaf(w1r[9 + k], xv.w, a1);
          a2 = fmaf(w2r[0 + k], xv.x, a2);
          a2 = fmaf(w2r[3 + k], xv.y, a2);
          a2 = fmaf(w2r[6 + k], xv.z, a2);
          a2 = fmaf(w2r[9 + k], xv.w, a2);
          a3 = fmaf(w3r[0 + k], xv.x, a3);
          a3 = fmaf(w3r[3 + k], xv.y, a3);
          a3 = fmaf(w3r[6 + k], xv.z, a3);
          a3 = fmaf(w3r[9 + k], xv.w, a3);
        }
        acc0[j] = a0; acc1[j] = a1; acc2[j] = a2; acc3[j] = a3;
      }
    }
  }
  size_t obase = (size_t)b * 65536 + t0 + tt0;
  float* op;
  op = out + obase + (size_t)c0 * 1024;
  *(float4*)op = make_float4(acc0[0], acc0[1], acc0[2], acc0[3]);
  *(float4*)(op + 4) = make_float4(acc0[4], acc0[5], acc0[6], acc0[7]);
  op = out + obase + (size_t)c1 * 1024;
  *(float4*)op = make_float4(acc1[0], acc1[1], acc1[2], acc1[3]);
  *(float4*)(op + 4) = make_float4(acc1[4], acc1[5], acc1[6], acc1[7]);
  op = out + obase + (size_t)c2 * 1024;
  *(float4*)op = make_float4(acc2[0], acc2[1], acc2[2], acc2[3]);
  *(float4*)(op + 4) = make_float4(acc2[4], acc2[5], acc2[6], acc2[7]);
  op = out + obase + (size_t)c3 * 1024;
  *(float4*)op = make_float4(acc3[0], acc3[1], acc3[2], acc3[3]);
  *(float4*)(op + 4) = make_float4(acc3[4], acc3[5], acc3[6], acc3[7]);
}

// ---------------------------------------------------------------------------
// full attention, split-K partials, no-max softmax (scores bounded ~1)
// 128 threads, 2 q per thread (l0 = blk*256+tid, l1 = l0+128), 2 s per iter.
// ---------------------------------------------------------------------------
__global__ __launch_bounds__(128, 2)
void attn_full_part(const float* __restrict__ Q, const float* __restrict__ K,
                    const float* __restrict__ V, float* __restrict__ part,
                    int stile, int nstage) {
  __shared__ float Ks[128][32];
  __shared__ float Vs[128][32];
  int bh = blockIdx.z, b = bh >> 1, h = bh & 1;
  int tid = threadIdx.x;                // 128
  int l0 = blockIdx.x * 256 + tid;
  int s0 = blockIdx.y * stile;
  const float* Kb = K + (size_t)b * 65536 + h * 32;
  const float* Vb = V + (size_t)b * 65536 + h * 32;
  const float* Qb0 = Q + (size_t)b * 65536 + h * 32 + (size_t)l0 * 64;
  const float* Qb1 = Qb0 + 128 * 64;
  float qa[32], qb[32];
  #pragma unroll
  for (int i = 0; i < 8; ++i) {
    float4 v4 = ((const float4*)Qb0)[i];
    qa[4*i] = v4.x; qa[4*i+1] = v4.y; qa[4*i+2] = v4.z; qa[4*i+3] = v4.w;
    float4 w4 = ((const float4*)Qb1)[i];
    qb[4*i] = w4.x; qb[4*i+1] = w4.y; qb[4*i+2] = w4.z; qb[4*i+3] = w4.w;
  }
  float oa[32], ob[32];
  #pragma unroll
  for (int d = 0; d < 32; ++d) { oa[d] = 0.0f; ob[d] = 0.0f; }
  float ssa = 0.0f, ssb = 0.0f;
  for (int st = 0; st < nstage; ++st) {
    __syncthreads();
    int sb = s0 + st * 128;
    for (int i = tid; i < 1024; i += 128) {
      int r = i >> 3, d4 = i & 7;
      ((float4*)&Ks[r][0])[d4] = *(const float4*)(Kb + (size_t)(sb + r) * 64 + d4 * 4);
      ((float4*)&Vs[r][0])[d4] = *(const float4*)(Vb + (size_t)(sb + r) * 64 + d4 * 4);
    }
    __syncthreads();
    for (int s = 0; s < 128; s += 2) {
      const float4* kp0 = (const float4*)&Ks[s][0];
      const float4* kp1 = (const float4*)&Ks[s + 1][0];
      float a0 = 0, a1 = 0, a2 = 0, a3 = 0;
      float c0 = 0, c1 = 0, c2 = 0, c3 = 0;
      float e0 = 0, e1 = 0, e2 = 0, e3 = 0;
      float g0 = 0, g1 = 0, g2 = 0, g3 = 0;
      #pragma unroll
      for (int i = 0; i < 8; ++i) {
        float4 k0 = kp0[i], k1 = kp1[i];
        float qx = qa[4*i], qy = qa[4*i+1], qz = qa[4*i+2], qw = qa[4*i+3];
        a0 = fmaf(qx, k0.x, a0); a1 = fmaf(qy, k0.y, a1);
        a2 = fmaf(qz, k0.z, a2); a3 = fmaf(qw, k0.w, a3);
        c0 = fmaf(qx, k1.x, c0); c1 = fmaf(qy, k1.y, c1);
        c2 = fmaf(qz, k1.z, c2); c3 = fmaf(qw, k1.w, c3);
        qx = qb[4*i]; qy = qb[4*i+1]; qz = qb[4*i+2]; qw = qb[4*i+3];
        e0 = fmaf(qx, k0.x, e0); e1 = fmaf(qy, k0.y, e1);
        e2 = fmaf(qz, k0.z, e2); e3 = fmaf(qw, k0.w, e3);
        g0 = fmaf(qx, k1.x, g0); g1 = fmaf(qy, k1.y, g1);
        g2 = fmaf(qz, k1.z, g2); g3 = fmaf(qw, k1.w, g3);
      }
      float p0a = __expf(((a0 + a1) + (a2 + a3)) * SCALE_);
      float p1a = __expf(((c0 + c1) + (c2 + c3)) * SCALE_);
      float p0b = __expf(((e0 + e1) + (e2 + e3)) * SCALE_);
      float p1b = __expf(((g0 + g1) + (g2 + g3)) * SCALE_);
      ssa += p0a + p1a;
      ssb += p0b + p1b;
      const float4* vp0 = (const float4*)&Vs[s][0];
      const float4* vp1 = (const float4*)&Vs[s + 1][0];
      #pragma unroll
      for (int i = 0; i < 8; ++i) {
        float4 v0 = vp0[i], v1 = vp1[i];
        oa[4*i]   = fmaf(p0a, v0.x, fmaf(p1a, v1.x, oa[4*i]));
        oa[4*i+1] = fmaf(p0a, v0.y, fmaf(p1a, v1.y, oa[4*i+1]));
        oa[4*i+2] = fmaf(p0a, v0.z, fmaf(p1a, v1.z, oa[4*i+2]));
        oa[4*i+3] = fmaf(p0a, v0.w, fmaf(p1a, v1.w, oa[4*i+3]));
        ob[4*i]   = fmaf(p0b, v0.x, fmaf(p1b, v1.x, ob[4*i]));
        ob[4*i+1] = fmaf(p0b, v0.y, fmaf(p1b, v1.y, ob[4*i+1]));
        ob[4*i+2] = fmaf(p0b, v0.z, fmaf(p1b, v1.z, ob[4*i+2]));
        ob[4*i+3] = fmaf(p0b, v0.w, fmaf(p1b, v1.w, ob[4*i+3]));
      }
    }
  }
  float* pp = part + (((size_t)bh * gridDim.y + blockIdx.y) * 1024 + l0) * 36;
  #pragma unroll
  for (int i = 0; i < 8; ++i)
    ((float4*)pp)[i] = make_float4(oa[4*i], oa[4*i+1], oa[4*i+2], oa[4*i+3]);
  pp[32] = ssa;
  pp = part + (((size_t)bh * gridDim.y + blockIdx.y) * 1024 + l0 + 128) * 36;
  #pragma unroll
  for (int i = 0; i < 8; ++i)
    ((float4*)pp)[i] = make_float4(ob[4*i], ob[4*i+1], ob[4*i+2], ob[4*i+3]);
  pp[32] = ssb;
}

__global__ void attn_full_comb(const float* __restrict__ part, float* __restrict__ cbuf,
                               int nsplit) {
  int idx = blockIdx.x * 128 + threadIdx.x;
  int bh = idx >> 10, l = idx & 1023;
  int b = bh >> 1, h = bh & 1;
  float S = 0.0f;
  float o[32];
  #pragma unroll
  for (int d = 0; d < 32; ++d) o[d] = 0.0f;
  for (int j = 0; j < nsplit; ++j) {
    const float* pp = part + (((size_t)bh * nsplit + j) * 1024 + l) * 36;
    S += pp[32];
    #pragma unroll
    for (int i = 0; i < 8; ++i) {
      float4 v4 = ((const float4*)pp)[i];
      o[4*i] += v4.x; o[4*i+1] += v4.y; o[4*i+2] += v4.z; o[4*i+3] += v4.w;
    }
  }
  float inv = 1.0f / S;
  float* cc = cbuf + ((size_t)b * 1024 + l) * 352 + 0 + h * 32;
  #pragma unroll
  for (int d = 0; d < 32; ++d) cc[d] = o[d] * inv;
}

// ---------------------------------------------------------------------------
// log-sparse attention, single-pass no-max
// ---------------------------------------------------------------------------
__global__ void attn_log_kernel(const float* __restrict__ Q, const float* __restrict__ K,
                                const float* __restrict__ V, float* __restrict__ cbuf) {
  int idx = blockIdx.x * 128 + threadIdx.x;
  int bh = idx >> 10, l = idx & 1023;
  int b = bh >> 1, h = bh & 1;
  const float* Qb = Q + (size_t)b * 65536 + h * 32;
  const float* Kb = K + (size_t)b * 65536 + h * 32;
  const float* Vb = V + (size_t)b * 65536 + h * 32;
  float q[32];
  #pragma unroll
  for (int i = 0; i < 8; ++i) {
    float4 v4 = ((const float4*)(Qb + (size_t)l * 64))[i];
    q[4*i] = v4.x; q[4*i+1] = v4.y; q[4*i+2] = v4.z; q[4*i+3] = v4.w;
  }
  float o[32];
  #pragma unroll
  for (int d = 0; d < 32; ++d) o[d] = 0.0f;
  float ssum = 0.0f;
  #pragma unroll
  for (int j = 0; j < 11; ++j) {
    int off = (j == 0) ? 0 : (1 << (j - 1));
    if (off <= l) {
      int s = l - off;
      const float4* kp = (const float4*)(Kb + (size_t)s * 64);
      float a0 = 0, a1 = 0, a2 = 0, a3 = 0;
      #pragma unroll
      for (int i = 0; i < 8; ++i) {
        float4 kv = kp[i];
        a0 = fmaf(q[4*i], kv.x, a0);
        a1 = fmaf(q[4*i+1], kv.y, a1);
        a2 = fmaf(q[4*i+2], kv.z, a2);
        a3 = fmaf(q[4*i+3], kv.w, a3);
      }
      float p = __expf(((a0 + a1) + (a2 + a3)) * SCALE_);
      ssum += p;
      const float4* vp = (const float4*)(Vb + (size_t)s * 64);
      #pragma unroll
      for (int i = 0; i < 8; ++i) {
        float4 vv = vp[i];
        o[4*i]   = fmaf(p, vv.x, o[4*i]);
        o[4*i+1] = fmaf(p, vv.y, o[4*i+1]);
        o[4*i+2] = fmaf(p, vv.z, o[4*i+2]);
        o[4*i+3] = fmaf(p, vv.w, o[4*i+3]);
      }
    }
  }
  float inv = 1.0f / ssum;
  float* cc = cbuf + ((size_t)b * 1024 + l) * 352 + 64 + h * 32;
  #pragma unroll
  for (int d = 0; d < 32; ++d) cc[d] = o[d] * inv;
}

// local-window attention, single-pass no-max
__global__ void attn_loc_kernel(const float* __restrict__ Q, const float* __restrict__ K,
                                const float* __restrict__ V, float* __restrict__ cbuf) {
  int idx = blockIdx.x * 128 + threadIdx.x;
  int bh = idx >> 10, l = idx & 1023;
  int b = bh >> 1, h = bh & 1;
  const float* Qb = Q + (size_t)b * 65536 + h * 32;
  const float* Kb = K + (size_t)b * 65536 + h * 32;
  const float* Vb = V + (size_t)b * 65536 + h * 32;
  float q[32];
  #pragma unroll
  for (int i = 0; i < 8; ++i) {
    float4 v4 = ((const float4*)(Qb + (size_t)l * 64))[i];
    q[4*i] = v4.x; q[4*i+1] = v4.y; q[4*i+2] = v4.z; q[4*i+3] = v4.w;
  }
  float o[32];
  #pragma unroll
  for (int d = 0; d < 32; ++d) o[d] = 0.0f;
  float ssum = 0.0f;
  int jlo = (l >= 31) ? 0 : (31 - l);
  for (int j = jlo; j < 32; ++j) {
    int s = l - 31 + j;
    const float4* kp = (const float4*)(Kb + (size_t)s * 64);
    float a0 = 0, a1 = 0, a2 = 0, a3 = 0;
    #pragma unroll
    for (int i = 0; i < 8; ++i) {
      float4 kv = kp[i];
      a0 = fmaf(q[4*i], kv.x, a0);
      a1 = fmaf(q[4*i+1], kv.y, a1);
      a2 = fmaf(q[4*i+2], kv.z, a2);
      a3 = fmaf(q[4*i+3], kv.w, a3);
    }
    float p = __expf(((a0 + a1) + (a2 + a3)) * SCALE_);
    ssum += p;
    const float4* vp = (const float4*)(Vb + (size_t)s * 64);
    #pragma unroll
    for (int i = 0; i < 8; ++i) {
      float4 vv = vp[i];
      o[4*i]   = fmaf(p, vv.x, o[4*i]);
      o[4*i+1] = fmaf(p, vv.y, o[4*i+1]);
      o[4*i+2] = fmaf(p, vv.z, o[4*i+2]);
      o[4*i+3] = fmaf(p, vv.w, o[4*i+3]);
    }
  }
  float inv = 1.0f / ssum;
  float* cc = cbuf + ((size_t)b * 1024 + l) * 352 + 128 + h * 32;
  #pragma unroll
  for (int d = 0; d < 32; ++d) cc[d] = o[d] * inv;
}

// ---------------------------------------------------------------------------
// prob-sparse attention
// ---------------------------------------------------------------------------
__global__ void prob_m_kernel(const float* __restrict__ Q, const float* __restrict__ K,
                              const int* __restrict__ pidx, float* __restrict__ Mbuf) {
  int idx = blockIdx.x * 128 + threadIdx.x;
  int bh = idx >> 10, l = idx & 1023;
  int b = bh >> 1, h = bh & 1;
  const float* Qb = Q + (size_t)b * 65536 + h * 32;
  const float* Kb = K + (size_t)b * 65536 + h * 32;
  float q[32];
  #pragma unroll
  for (int i = 0; i < 8; ++i) {
    float4 v4 = ((const float4*)(Qb + (size_t)l * 64))[i];
    q[4*i] = v4.x; q[4*i+1] = v4.y; q[4*i+2] = v4.z; q[4*i+3] = v4.w;
  }
  float mx = -1e30f, sm = 0.0f;
  for (int u = 0; u < 35; ++u) {
    int ki = pidx[l * 35 + u];
    const float4* kp = (const float4*)(Kb + (size_t)ki * 64);
    float a0 = 0, a1 = 0, a2 = 0, a3 = 0;
    #pragma unroll
    for (int i = 0; i < 8; ++i) {
      float4 kv = kp[i];
      a0 = fmaf(q[4*i], kv.x, a0);
      a1 = fmaf(q[4*i+1], kv.y, a1);
      a2 = fmaf(q[4*i+2], kv.z, a2);
      a3 = fmaf(q[4*i+3], kv.w, a3);
    }
    float s = (a0 + a1) + (a2 + a3);
    mx = fmaxf(mx, s);
    sm += s;
  }
  Mbuf[(size_t)bh * 1024 + l] = mx - sm * (1.0f / 1024.0f);
}

// single-wave register-resident top-35 (no barriers)
__global__ void top35_kernel(const float* __restrict__ Mbuf, int* __restrict__ sel) {
  int bh = blockIdx.x;
  int lane = threadIdx.x;        // 64 threads
  float v[16];
  const float* Mb = Mbuf + (size_t)bh * 1024 + lane * 16;
  #pragma unroll
  for (int k = 0; k < 16; ++k) v[k] = Mb[k];
  for (int it = 0; it < 35; ++it) {
    float bv = -1e30f; int bi = 0;
    #pragma unroll
    for (int k = 0; k < 16; ++k)
      if (v[k] > bv) { bv = v[k]; bi = k; }
    int gidx = lane * 16 + bi;
    #pragma unroll
    for (int off = 32; off > 0; off >>= 1) {
      float ov = __shfl_down(bv, off, 64);
      int og = __shfl_down(gidx, off, 64);
      if (ov > bv || (ov == bv && og < gidx)) { bv = ov; gidx = og; }
    }
    gidx = __shfl(gidx, 0, 64);
    if (lane == 0) sel[bh * 35 + it] = gidx;
    if ((gidx >> 4) == lane) {
      int kk = gidx & 15;
      #pragma unroll
      for (int k = 0; k < 16; ++k)
        if (k == kk) v[k] = -1e30f;
    }
  }
}

__global__ void prob_fill_kernel(const float* __restrict__ V, float* __restrict__ cbuf) {
  __shared__ float red[256];
  __shared__ float vm[32];
  int bh = blockIdx.x, b = bh >> 1, h = bh & 1;
  int tid = threadIdx.x;
  int d = tid & 31, ch = tid >> 5;
  const float* Vb = V + (size_t)b * 65536 + h * 32;
  float s = 0.0f;
  for (int ss = ch * 128; ss < ch * 128 + 128; ++ss) s += Vb[(size_t)ss * 64 + d];
  red[tid] = s;
  __syncthreads();
  if (ch == 0) {
    float t = 0.0f;
    for (int c = 0; c < 8; ++c) t += red[c * 32 + d];
    vm[d] = t * (1.0f / 1024.0f);
  }
  __syncthreads();
  for (int i = tid; i < 1024 * 32; i += 256) {
    int l = i >> 5, dd = i & 31;
    cbuf[((size_t)b * 1024 + l) * 352 + 192 + h * 32 + dd] = vm[dd];
  }
}

__global__ void prob_part_kernel(const float* __restrict__ Q, const float* __restrict__ K,
                                 const float* __restrict__ V, const int* __restrict__ sel,
                                 float* __restrict__ ppart) {
  int bh = blockIdx.y, b = bh >> 1, h = bh & 1;
  int sc0 = blockIdx.x * 64;
  int u = threadIdx.x;
  int uu = (u < 35) ? u : 34;
  int l = sel[bh * 35 + uu];
  const float* Qb = Q + (size_t)b * 65536 + h * 32;
  const float* Kb = K + (size_t)b * 65536 + h * 32;
  const float* Vb = V + (size_t)b * 65536 + h * 32;
  float q[32];
  #pragma unroll
  for (int i = 0; i < 8; ++i) {
    float4 v4 = ((const float4*)(Qb + (size_t)l * 64))[i];
    q[4*i] = v4.x; q[4*i+1] = v4.y; q[4*i+2] = v4.z; q[4*i+3] = v4.w;
  }
  float o[32];
  #pragma unroll
  for (int dd = 0; dd < 32; ++dd) o[dd] = 0.0f;
  float ssum = 0.0f;
  for (int s = sc0; s < sc0 + 64; ++s) {
    const float4* kp = (const float4*)(Kb + (size_t)s * 64);
    float a0 = 0, a1 = 0, a2 = 0, a3 = 0;
    #pragma unroll
    for (int i = 0; i < 8; ++i) {
      float4 kv = kp[i];
      a0 = fmaf(q[4*i], kv.x, a0);
      a1 = fmaf(q[4*i+1], kv.y, a1);
      a2 = fmaf(q[4*i+2], kv.z, a2);
      a3 = fmaf(q[4*i+3], kv.w, a3);
    }
    float p = __expf(((a0 + a1) + (a2 + a3)) * SCALE_);
    ssum += p;
    const float4* vp = (const float4*)(Vb + (size_t)s * 64);
    #pragma unroll
    for (int i = 0; i < 8; ++i) {
      float4 vv = vp[i];
      o[4*i]   = fmaf(p, vv.x, o[4*i]);
      o[4*i+1] = fmaf(p, vv.y, o[4*i+1]);
      o[4*i+2] = fmaf(p, vv.z, o[4*i+2]);
      o[4*i+3] = fmaf(p, vv.w, o[4*i+3]);
    }
  }
  if (u < 35) {
    float* pp = ppart + (((size_t)bh * 16 + blockIdx.x) * 35 + u) * 36;
    #pragma unroll
    for (int i = 0; i < 8; ++i)
      ((float4*)pp)[i] = make_float4(o[4*i], o[4*i+1], o[4*i+2], o[4*i+3]);
    pp[32] = ssum;
  }
}

__global__ void prob_comb_kernel(const float* __restrict__ ppart, const int* __restrict__ sel,
                                 float* __restrict__ cbuf) {
  int t = blockIdx.x * 64 + threadIdx.x;
  if (t >= 32 * 35) return;
  int bh = t / 35, u = t % 35;
  int b = bh >> 1, h = bh & 1;
  int l = sel[bh * 35 + u];
  float S = 0.0f;
  float o[32];
  #pragma unroll
  for (int d = 0; d < 32; ++d) o[d] = 0.0f;
  for (int j = 0; j < 16; ++j) {
    const float* pp = ppart + (((size_t)bh * 16 + j) * 35 + u) * 36;
    S += pp[32];
    #pragma unroll
    for (int i = 0; i < 8; ++i) {
      float4 v4 = ((const float4*)pp)[i];
      o[4*i] += v4.x; o[4*i+1] += v4.y; o[4*i+2] += v4.z; o[4*i+3] += v4.w;
    }
  }
  float inv = 1.0f / S;
  float* cc = cbuf + ((size_t)b * 1024 + l) * 352 + 192 + h * 32;
  #pragma unroll
  for (int d = 0; d < 32; ++d) cc[d] = o[d] * inv;
}

// ---------------------------------------------------------------------------
// autocorrelation: mv[b,tau] = (1/64) sum_{c,t} K[b,c,t] * Q[b,c,(t+tau)%1024]
// 128 threads, 8 taus/thread, rolling 16-float q window, swizzled b128 reads.
// ---------------------------------------------------------------------------
__global__ void auto_mv_part(const float* __restrict__ Qa, const float* __restrict__ Ka,
                             float* __restrict__ part) {
  __shared__ float4 qs4[512];
  int c = blockIdx.x, b = blockIdx.y;
  int tid = threadIdx.x;         // 128
  const float* Qb = Qa + (size_t)b * 65536 + (size_t)c * 1024;
  const float* Kb = Ka + (size_t)b * 65536 + (size_t)c * 1024;
  const float4* Qb4 = (const float4*)Qb;
  for (int blk = tid; blk < 512; blk += 128) {
    int pb = blk ^ ((blk >> 3) & 7);
    qs4[pb] = Qb4[blk & 255];
  }
  __syncthreads();
  float acc[8];
  #pragma unroll
  for (int j = 0; j < 8; ++j) acc[j] = 0.0f;
  int base = 2 * tid;
  float4 v0, v1;
  {
    int b0 = base, b1 = base + 1;
    v0 = qs4[b0 ^ ((b0 >> 3) & 7)];
    v1 = qs4[b1 ^ ((b1 >> 3) & 7)];
  }
  for (int t = 0; t < 1024; t += 8) {
    int b2 = (t >> 2) + base + 2, b3 = b2 + 1;
    float4 v2 = qs4[b2 ^ ((b2 >> 3) & 7)];
    float4 v3 = qs4[b3 ^ ((b3 >> 3) & 7)];
    float4 k0 = *(const float4*)(Kb + t);
    float4 k1 = *(const float4*)(Kb + t + 4);
    float W[16] = {v0.x, v0.y, v0.z, v0.w, v1.x, v1.y, v1.z, v1.w,
                   v2.x, v2.y, v2.z, v2.w, v3.x, v3.y, v3.z, v3.w};
    float K8[8] = {k0.x, k0.y, k0.z, k0.w, k1.x, k1.y, k1.z, k1.w};
    #pragma unroll
    for (int j = 0; j < 8; ++j) {
      float a = acc[j];
      #pragma unroll
      for (int i = 0; i < 8; ++i) a = fmaf(K8[i], W[j + i], a);
      acc[j] = a;
    }
    v0 = v2; v1 = v3;
  }
  float* pp = &part[(((size_t)b * 64 + c) << 10) + tid * 8];
  *(float4*)pp = make_float4(acc[0], acc[1], acc[2], acc[3]);
  *(float4*)(pp + 4) = make_float4(acc[4], acc[5], acc[6], acc[7]);
}

__global__ void auto_mv_reduce(const float* __restrict__ part, float* __restrict__ mv) {
  int idx = blockIdx.x * 256 + threadIdx.x;
  int b = idx >> 10, tau = idx & 1023;
  float s = 0.0f;
  for (int c = 0; c < 64; ++c) s += part[(((size_t)b * 64 + c) << 10) + tau];
  mv[(size_t)b * 1024 + tau] = s * (1.0f / 64.0f);
}

// single-wave top-6 + per-batch softmax weights
__global__ void auto_top6_kernel(const float* __restrict__ mv, int* __restrict__ idx6,
                                 float* __restrict__ w6) {
  __shared__ int id6s[6];
  int lane = threadIdx.x;     // 64 threads
  float v[16];
  #pragma unroll
  for (int k = 0; k < 16; ++k) {
    int i = lane * 16 + k;
    float s = 0.0f;
    for (int b = 0; b < 16; ++b) s += mv[(size_t)b * 1024 + i];
    v[k] = s;
  }
  for (int it = 0; it < 6; ++it) {
    float bv = -1e30f; int bi = 0;
    #pragma unroll
    for (int k = 0; k < 16; ++k)
      if (v[k] > bv) { bv = v[k]; bi = k; }
    int gidx = lane * 16 + bi;
    #pragma unroll
    for (int off = 32; off > 0; off >>= 1) {
      float ov = __shfl_down(bv, off, 64);
      int og = __shfl_down(gidx, off, 64);
      if (ov > bv || (ov == bv && og < gidx)) { bv = ov; gidx = og; }
    }
    gidx = __shfl(gidx, 0, 64);
    if (lane == 0) { idx6[it] = gidx; id6s[it] = gidx; }
    if ((gidx >> 4) == lane) {
      int kk = gidx & 15;
      #pragma unroll
      for (int k = 0; k < 16; ++k)
        if (k == kk) v[k] = -1e30f;
    }
  }
  __syncthreads();
  if (lane < 16) {
    int b = lane;
    float vals[6]; float mx = -1e30f;
    #pragma unroll
    for (int j = 0; j < 6; ++j) { vals[j] = mv[(size_t)b * 1024 + id6s[j]]; mx = fmaxf(mx, vals[j]); }
    float s = 0.0f;
    #pragma unroll
    for (int j = 0; j < 6; ++j) { vals[j] = __expf(vals[j] - mx); s += vals[j]; }
    #pragma unroll
    for (int j = 0; j < 6; ++j) w6[b * 6 + j] = vals[j] / s;
  }
}

__global__ void auto_agg_kernel(const float* __restrict__ Va, const float* __restrict__ iq,
                                const float* __restrict__ wap, const float* __restrict__ bap,
                                const int* __restrict__ idx6, const float* __restrict__ w6,
                                float* __restrict__ ca) {
  __shared__ float aggs[16][64];
  __shared__ float w6s[6];
  __shared__ int id6[6];
  int b = blockIdx.y, t0 = blockIdx.x * 16;
  int tid = threadIdx.x;
  if (tid < 6) { w6s[tid] = w6[b * 6 + tid]; id6[tid] = idx6[tid]; }
  __syncthreads();
  const float* Vb = Va + (size_t)b * 65536;
  for (int i = tid; i < 1024; i += 256) {
    int tl = i >> 6, c = i & 63;
    int t = t0 + tl;
    float s = 0.0f;
    #pragma unroll
    for (int j = 0; j < 6; ++j)
      s += w6s[j] * Vb[(size_t)((t + id6[j]) & 1023) * 64 + c];
    aggs[tl][c] = s;
  }
  __syncthreads();
  int dm = tid & 127, tp = tid >> 7;
  float acc[8];
  #pragma unroll
  for (int r = 0; r < 8; ++r) {
    int t = t0 + tp * 8 + r;
    acc[r] = bap[dm] + iq[((size_t)b * 1024 + t) * 128 + dm];
  }
  for (int c = 0; c < 64; ++c) {
    float wv = wap[c * 128 + dm];
    #pragma unroll
    for (int r = 0; r < 8; ++r) acc[r] += aggs[tp * 8 + r][c] * wv;
  }
  #pragma unroll
  for (int r = 0; r < 8; ++r)
    ca[((size_t)b * 1024 + t0 + tp * 8 + r) * 128 + dm] = acc[r];
}

// moving-average detrend (k=25, edge-replicate, running window) + asize proj
__global__ void auto_ma_kernel(const float* __restrict__ ca, const float* __restrict__ was,
                               const float* __restrict__ bas, float* __restrict__ cbuf) {
  __shared__ float cas[40][128];
  __shared__ float diff[16][128];
  int b = blockIdx.y, t0 = blockIdx.x * 16;
  int tid = threadIdx.x;
  for (int i = tid; i < 40 * 128; i += 256) {
    int r = i >> 7, d = i & 127;
    int t = t0 - 12 + r;
    t = (t < 0) ? 0 : ((t > 1023) ? 1023 : t);
    cas[r][d] = ca[((size_t)b * 1024 + t) * 128 + d];
  }
  __syncthreads();
  int d = tid & 127, hf = tid >> 7;
  int tl0 = hf * 8;
  float s = 0.0f;
  #pragma unroll
  for (int w = 0; w < 25; ++w) s += cas[tl0 + w][d];
  #pragma unroll
  for (int k = 0; k < 8; ++k) {
    int tl = tl0 + k;
    diff[tl][d] = cas[tl + 12][d] - s * (1.0f / 25.0f);
    if (k < 7) s += cas[tl + 25][d] - cas[tl][d];
  }
  __syncthreads();
  int j = tid & 63, tq = tid >> 6;
  float acc[4];
  #pragma unroll
  for (int r = 0; r < 4; ++r) acc[r] = bas[j];
  for (int dd = 0; dd < 128; ++dd) {
    float wv = was[dd * 64 + j];
    #pragma unroll
    for (int r = 0; r < 4; ++r) acc[r] += diff[tq * 4 + r][dd] * wv;
  }
  #pragma unroll
  for (int r = 0; r < 4; ++r)
    cbuf[((size_t)b * 1024 + t0 + tq * 4 + r) * 352 + 288 + j] = acc[r];
}

// ---------------------------------------------------------------------------
// FFT branch: Y = X @ wfft, then cf_proj[f] = sum_t cos(2pi f t/1024) Y[t]
// symmetry: cf[1024-f] == cf[f]; f=512 (alternating sum) fused into block x=0
// ---------------------------------------------------------------------------
__global__ void fftY_kernel(const float* __restrict__ x, const float* __restrict__ wfft,
                            float* __restrict__ Y) {
  __shared__ float xs[64][128];
  __shared__ float ws[32][129];
  int b = blockIdx.y, t0 = blockIdx.x * 64;
  int tid = threadIdx.x;
  for (int i = tid; i < 64 * 128; i += 256) {
    int r = i >> 7, d = i & 127;
    xs[r][d] = x[(size_t)b * 131072 + (size_t)(t0 + r) * 128 + d];
  }
  for (int i = tid; i < 4096; i += 256) {
    int d = i >> 5, j = i & 31;
    ws[j][d] = wfft[i];
  }
  __syncthreads();
  int j = tid & 31, tt0 = (tid >> 5) * 8;
  float acc[8];
  #pragma unroll
  for (int r = 0; r < 8; ++r) acc[r] = 0.0f;
  for (int d0 = 0; d0 < 128; d0 += 4) {
    float w0 = ws[j][d0], w1 = ws[j][d0 + 1], w2 = ws[j][d0 + 2], w3 = ws[j][d0 + 3];
    #pragma unroll
    for (int r = 0; r < 8; ++r) {
      float4 xv = *(const float4*)&xs[tt0 + r][d0];
      float a = acc[r];
      a = fmaf(w0, xv.x, a);
      a = fmaf(w1, xv.y, a);
      a = fmaf(w2, xv.z, a);
      a = fmaf(w3, xv.w, a);
      acc[r] = a;
    }
  }
  #pragma unroll
  for (int r = 0; r < 8; ++r)
    Y[((size_t)b * 1024 + t0 + tt0 + r) * 32 + j] = acc[r];
}

__global__ void fftT_kernel(const float* __restrict__ Y, const float* __restrict__ bfft,
                            float* __restrict__ cbuf) {
  __shared__ float ys[256 * 32];
  __shared__ float altred[8][32];
  int b = blockIdx.y, fbase = blockIdx.x * 64;
  int tid = threadIdx.x;
  int fi = tid & 31, jg = tid >> 5, j0 = jg * 4;
  int f0 = fbase + fi * 2;
  const float TWO_PI_N = 6.283185307179586476925f / 1024.0f;
  float ca0, sa0, ca1, sa1;
  sincosf(TWO_PI_N * (float)f0, &sa0, &ca0);
  sincosf(TWO_PI_N * (float)(f0 + 1), &sa1, &ca1);
  float cr0 = 1.0f, ci0 = 0.0f, cr1 = 1.0f, ci1 = 0.0f;
  float4 acc0 = make_float4(0.f, 0.f, 0.f, 0.f);
  float4 acc1 = make_float4(0.f, 0.f, 0.f, 0.f);
  bool do512 = (blockIdx.x == 0);
  int aj = tid & 31, arow = tid >> 5;
  float alt = 0.0f;
  for (int chk = 0; chk < 4; ++chk) {
    __syncthreads();
    const float4* Yp = (const float4*)(Y + ((size_t)b * 1024 + chk * 256) * 32);
    for (int i = tid; i < 2048; i += 256) ((float4*)ys)[i] = Yp[i];
    __syncthreads();
    for (int tl = 0; tl < 256; ++tl) {
      float4 yv = *(const float4*)&ys[tl * 32 + j0];
      acc0.x = fmaf(cr0, yv.x, acc0.x);
      acc0.y = fmaf(cr0, yv.y, acc0.y);
      acc0.z = fmaf(cr0, yv.z, acc0.z);
      acc0.w = fmaf(cr0, yv.w, acc0.w);
      acc1.x = fmaf(cr1, yv.x, acc1.x);
      acc1.y = fmaf(cr1, yv.y, acc1.y);
      acc1.z = fmaf(cr1, yv.z, acc1.z);
      acc1.w = fmaf(cr1, yv.w, acc1.w);
      float nr0 = cr0 * ca0 - ci0 * sa0;
      float ni0 = cr0 * sa0 + ci0 * ca0;
      cr0 = nr0; ci0 = ni0;
      float nr1 = cr1 * ca1 - ci1 * sa1;
      float ni1 = cr1 * sa1 + ci1 * ca1;
      cr1 = nr1; ci1 = ni1;
    }
    if (do512) {
      int tb = arow * 32;
      #pragma unroll 8
      for (int k = 0; k < 32; ++k) {
        float y = ys[(tb + k) * 32 + aj];
        alt += ((tb + k) & 1) ? -y : y;
      }
    }
  }
  float b0 = bfft[j0], b1 = bfft[j0 + 1], b2 = bfft[j0 + 2], b3 = bfft[j0 + 3];
  float* cc0 = cbuf + ((size_t)b * 1024 + f0) * 352 + 256 + j0;
  cc0[0] = acc0.x + b0; cc0[1] = acc0.y + b1; cc0[2] = acc0.z + b2; cc0[3] = acc0.w + b3;
  float* cc1 = cbuf + ((size_t)b * 1024 + f0 + 1) * 352 + 256 + j0;
  cc1[0] = acc1.x + b0; cc1[1] = acc1.y + b1; cc1[2] = acc1.z + b2; cc1[3] = acc1.w + b3;
  if (f0 > 0) {
    float* cm0 = cbuf + ((size_t)b * 1024 + (1024 - f0)) * 352 + 256 + j0;
    cm0[0] = acc0.x + b0; cm0[1] = acc0.y + b1; cm0[2] = acc0.z + b2; cm0[3] = acc0.w + b3;
  }
  {
    float* cm1 = cbuf + ((size_t)b * 1024 + (1024 - f0 - 1)) * 352 + 256 + j0;
    cm1[0] = acc1.x + b0; cm1[1] = acc1.y + b1; cm1[2] = acc1.z + b2; cm1[3] = acc1.w + b3;
  }
  if (do512) {
    altred[arow][aj] = alt;
    __syncthreads();
    if (tid < 32) {
      float s = 0.0f;
      #pragma unroll
      for (int r = 0; r < 8; ++r) s += altred[r][tid];
      cbuf[((size_t)b * 1024 + 512) * 352 + 256 + tid] = s + bfft[tid];
    }
  }
}

// ---------------------------------------------------------------------------
// final: out = cbuf @ w_fc + iq, then layernorm over DM
// ---------------------------------------------------------------------------
__global__ void fc_ln_kernel(const float* __restrict__ cbuf, const float* __restrict__ wfc,
                             const float* __restrict__ iq, float* __restrict__ out) {
  __shared__ float cs[16][352];
  __shared__ float os[16][128];
  int b = blockIdx.y, t0 = blockIdx.x * 16;
  int tid = threadIdx.x;
  for (int i = tid; i < 16 * 352; i += 256) {
    int r = i / 352, col = i % 352;
    cs[r][col] = cbuf[((size_t)b * 1024 + t0 + r) * 352 + col];
  }
  __syncthreads();
  int j = tid & 127, half = tid >> 7;
  float acc[8];
  #pragma unroll
  for (int k = 0; k < 8; ++k)
    acc[k] = iq[((size_t)b * 1024 + t0 + half * 8 + k) * 128 + j];
  for (int i = 0; i < 352; ++i) {
    float wv = wfc[i * 128 + j];
    #pragma unroll
    for (int k = 0; k < 8; ++k) acc[k] += cs[half * 8 + k][i] * wv;
  }
  #pragma unroll
  for (int k = 0; k < 8; ++k) os[half * 8 + k][j] = acc[k];
  __syncthreads();
  int wid = tid >> 6, lane = tid & 63;
  for (int rr = 0; rr < 4; ++rr) {
    int r = wid * 4 + rr;
    float x0 = os[r][lane], x1 = os[r][lane + 64];
    float s1 = x0 + x1;
    float s2 = x0 * x0 + x1 * x1;
    #pragma unroll
    for (int k = 32; k > 0; k >>= 1) {
      s1 += __shfl_xor(s1, k, 64);
      s2 += __shfl_xor(s2, k, 64);
    }
    float mean = s1 * (1.0f / 128.0f);
    float var = s2 * (1.0f / 128.0f) - mean * mean;
    float rstd = 1.0f / sqrtf(var + 1e-5f);
    float* op = out + ((size_t)b * 1024 + t0 + r) * 128;
    op[lane] = (x0 - mean) * rstd;
    op[lane + 64] = (x1 - mean) * rstd;
  }
}

// ---------------------------------------------------------------------------
extern "C" void kernel_launch(void* const* d_in, const int* in_sizes, int n_in,
                              void* d_out, int out_size, void* d_ws, size_t ws_size,
                              hipStream_t stream) {
  (void)in_sizes; (void)n_in; (void)out_size;
  const float* inQ = (const float*)d_in[0];
  const float* inK = (const float*)d_in[1];
  const float* inV = (const float*)d_in[2];
  const float *wq[5], *bq[5], *wk[5], *bk[5], *wv[5], *bv[5];
  for (int br = 0; br < 5; ++br) {
    wq[br] = (const float*)d_in[3 + br * 6 + 0];
    bq[br] = (const float*)d_in[3 + br * 6 + 1];
    wk[br] = (const float*)d_in[3 + br * 6 + 2];
    bk[br] = (const float*)d_in[3 + br * 6 + 3];
    wv[br] = (const float*)d_in[3 + br * 6 + 4];
    bv[br] = (const float*)d_in[3 + br * 6 + 5];
  }
  const float* wfft = (const float*)d_in[33];
  const float* bfft = (const float*)d_in[34];
  const float* wap  = (const float*)d_in[35];
  const float* bap  = (const float*)d_in[36];
  const float* was  = (const float*)d_in[37];
  const float* bas  = (const float*)d_in[38];
  const float* wfc  = (const float*)d_in[39];
  float* out = (float*)d_out;

  bool mega = ws_size >= (size_t)128 * 1024 * 1024;
  int nsplit = (ws_size >= (size_t)76 * 1024 * 1024) ? 8 : 4;
  int stile = 1024 / nsplit;
  int nstage = stile / 128;

  char* wsb = (char*)d_ws;
  size_t off = 0;
  auto alloc = [&](size_t bytes) -> void* {
    void* p = wsb + off;
    off += (bytes + 255) & ~(size_t)255;
    return p;
  };
  int*   pidx = (int*)  alloc((size_t)35840 * 4);
  float* qkvall = (float*)alloc((size_t)(mega ? 15 : 3) * 1048576 * 4);
  float* cbuf = (float*)alloc((size_t)16 * 1024 * 352 * 4);
  float* fpart = (float*)alloc((size_t)32 * nsplit * 1024 * 36 * 4);
  float* Mbuf = (float*)alloc((size_t)32 * 1024 * 4);
  int*   sel  = (int*)  alloc((size_t)32 * 35 * 4);
  float* mvb  = (float*)alloc((size_t)16 * 1024 * 4);
  int*   idx6 = (int*)  alloc(64);
  float* w6   = (float*)alloc((size_t)16 * 6 * 4);
  // aliases into fpart (timeline-disjoint):
  float* ppart = fpart;                                              // prob partials
  float* cab   = fpart;                                              // auto ca (8MiB)
  float* mpart = (float*)((char*)fpart + (size_t)8 * 1024 * 1024);   // corr partials (4MiB)
  float* Ybuf  = (float*)((char*)fpart + (size_t)12 * 1024 * 1024);  // fft Y (2MiB)

  mt_kernel<<<1, 256, 0, stream>>>(pidx);

  if (mega) {
    ConvArgs ca;
    ca.x[0] = inQ; ca.x[1] = inK; ca.x[2] = inV;
    for (int br = 0; br < 5; ++br) {
      ca.w[br * 3 + 0] = wq[br]; ca.bia[br * 3 + 0] = bq[br];
      ca.w[br * 3 + 1] = wk[br]; ca.bia[br * 3 + 1] = bk[br];
      ca.w[br * 3 + 2] = wv[br]; ca.bia[br * 3 + 2] = bv[br];
    }
    ca.outbase = qkvall;
    conv3_mega<<<dim3(8, 16, 10), 256, 0, stream>>>(ca);
    conv1_mega<<<dim3(16, 16, 5), 256, 0, stream>>>(ca);
  }
  auto bufs = [&](int br, float*& qb, float*& kb, float*& vb) {
    int bi = mega ? br : 0;
    qb = qkvall + (size_t)(bi * 3 + 0) * 1048576;
    kb = qkvall + (size_t)(bi * 3 + 1) * 1048576;
    vb = qkvall + (size_t)(bi * 3 + 2) * 1048576;
  };
  auto conv_branch = [&](int br, float* qb, float* kb, float* vb) {
    if (!mega)
      qkv_conv_kernel<<<dim3(16, 16, 3), 256, 0, stream>>>(
          inQ, inK, inV, wq[br], bq[br], wk[br], bk[br], wv[br], bv[br], qb, kb, vb);
  };
  float *qb, *kb, *vb;

  // branch 0: full attention
  bufs(0, qb, kb, vb);
  conv_branch(0, qb, kb, vb);
  attn_full_part<<<dim3(4, nsplit, 32), 128, 0, stream>>>(qb, kb, vb, fpart, stile, nstage);
  attn_full_comb<<<256, 128, 0, stream>>>(fpart, cbuf, nsplit);

  // branch 1: log-sparse
  bufs(1, qb, kb, vb);
  conv_branch(1, qb, kb, vb);
  attn_log_kernel<<<256, 128, 0, stream>>>(qb, kb, vb, cbuf);

  // branch 2: local window
  bufs(2, qb, kb, vb);
  conv_branch(2, qb, kb, vb);
  attn_loc_kernel<<<256, 128, 0, stream>>>(qb, kb, vb, cbuf);

  // branch 3: prob-sparse
  bufs(3, qb, kb, vb);
  conv_branch(3, qb, kb, vb);
  prob_m_kernel<<<256, 128, 0, stream>>>(qb, kb, pidx, Mbuf);
  top35_kernel<<<32, 64, 0, stream>>>(Mbuf, sel);
  prob_fill_kernel<<<32, 256, 0, stream>>>(vb, cbuf);
  prob_part_kernel<<<dim3(16, 32), 64, 0, stream>>>(qb, kb, vb, sel, ppart);
  prob_comb_kernel<<<18, 64, 0, stream>>>(ppart, sel, cbuf);

  // branch 4: autocorrelation
  bufs(4, qb, kb, vb);
  conv_branch(4, qb, kb, vb);
  auto_mv_part<<<dim3(64, 16), 128, 0, stream>>>(qb, kb, mpart);
  auto_mv_reduce<<<64, 256, 0, stream>>>(mpart, mvb);
  auto_top6_kernel<<<1, 64, 0, stream>>>(mvb, idx6, w6);
  auto_agg_kernel<<<dim3(64, 16), 256, 0, stream>>>(vb, inQ, wap, bap, idx6, w6, cab);
  auto_ma_kernel<<<dim3(64, 16), 256, 0, stream>>>(cab, was, bas, cbuf);

  // FFT branch (mirror symmetry; f=512 fused into fftT block x=0)
  fftY_kernel<<<dim3(16, 16), 256, 0, stream>>>(inQ, wfft, Ybuf);
  fftT_kernel<<<dim3(8, 16), 256, 0, stream>>>(Ybuf, bfft, cbuf);

  // final projection + layernorm
  fc_ln_kernel<<<dim3(64, 16), 256, 0, stream>>>(cbuf, wfc, inQ, out);
}